// Round 11
// baseline (155.887 us; speedup 1.0000x reference)
//
#include <hip/hip_runtime.h>

#define IN_CH 128
#define OUT_CH 10
#define SHIFT 10                   // nodes per bucket = 1024
#define NPB 1024
#define CHUNK_C 2048               // bincount chunk (256 thr)
#define CHUNK_F 4096               // binfill chunk (512 thr; runs ~42 pairs)
#define CCAP 4096                  // pairs per counting-sort round in k_accum
#define DSPL 8                     // deg slices per bucket

// bf16 helpers (RNE pack, shift unpack)
__device__ __forceinline__ unsigned pk2(float a, float b) {
    unsigned ua = __float_as_uint(a);
    ua = (ua + 0x7fffu + ((ua >> 16) & 1u)) >> 16;
    unsigned ub = __float_as_uint(b);
    ub = (ub + 0x7fffu + ((ub >> 16) & 1u)) >> 16;
    return ua | (ub << 16);
}
__device__ __forceinline__ float lo16(unsigned u) {
    return __uint_as_float(u << 16);
}
__device__ __forceinline__ float hi16(unsigned u) {
    return __uint_as_float(u & 0xffff0000u);
}

// ============================================================================
// Shared helpers
// ============================================================================

__device__ __forceinline__ int load_dst(const void* ei, bool is32, long long E,
                                        long long i) {
    return is32 ? ((const int*)ei)[E + i] : (int)((const long long*)ei)[E + i];
}
__device__ __forceinline__ int load_src(const void* ei, bool is32, long long E,
                                        long long i) {
    return is32 ? ((const int*)ei)[i] : (int)((const long long*)ei)[i];
}

// Fused: zero bcnt + int64/int32 detect (odd 32-bit words all zero -> int64).
__global__ void k_init(const unsigned int* __restrict__ w,
                       int* __restrict__ bcnt, int* __restrict__ flag, int NB,
                       int nwords_check) {
    __shared__ int any_nz;
    for (int i = threadIdx.x; i < NB; i += 256) bcnt[i] = 0;
    if (threadIdx.x == 0) any_nz = 0;
    __syncthreads();
    int local = 0;
    for (int i = threadIdx.x; i < nwords_check; i += 256)
        if (w[2 * i + 1] != 0u) local = 1;
    if (local) atomicOr(&any_nz, 1);
    __syncthreads();
    if (threadIdx.x == 0) *flag = any_nz;
}

__global__ void k_zero_i(int* __restrict__ p, int n) {
    int i = blockIdx.x * blockDim.x + threadIdx.x;
    int stride = gridDim.x * blockDim.x;
    for (; i < n; i += stride) p[i] = 0;
}

// ============================================================================
// Bucketed-gather path (primary)
// ============================================================================

// Per-chunk LDS histogram of buckets, one global atomic per bucket.
__global__ void k_bincount(const void* __restrict__ ei,
                           const int* __restrict__ flag, int E,
                           int* __restrict__ bcnt, int NB) {
    __shared__ int h[128];
    for (int i = threadIdx.x; i < NB; i += blockDim.x) h[i] = 0;
    __syncthreads();
    const bool is32 = (*flag != 0);
    long long base = (long long)blockIdx.x * CHUNK_C;
    int lim = (int)min((long long)CHUNK_C, (long long)E - base);
    for (int i = threadIdx.x; i < lim; i += blockDim.x) {
        int d = load_dst(ei, is32, E, base + i);
        atomicAdd(&h[d >> SHIFT], 1);
    }
    __syncthreads();
    for (int i = threadIdx.x; i < NB; i += blockDim.x)
        if (h[i]) atomicAdd(&bcnt[i], h[i]);
}

// Exclusive scan of bcnt[NB] (NB <= 128) -> bbase, gcursor
__global__ void k_scanNB(const int* __restrict__ bcnt, int* __restrict__ bbase,
                         int* __restrict__ gcur, int NB) {
    __shared__ int s[128];
    int tid = threadIdx.x;
    int v = (tid < NB) ? bcnt[tid] : 0;
    if (tid < 128) s[tid] = v;
    __syncthreads();
    for (int off = 1; off < 128; off <<= 1) {
        int t = (tid < 128 && tid >= off) ? s[tid - off] : 0;
        __syncthreads();
        if (tid < 128) s[tid] += t;
        __syncthreads();
    }
    if (tid < NB) {
        int e = s[tid] - v;
        bbase[tid] = e;
        gcur[tid] = e;
    }
}

// Per chunk (512 threads): LDS hist -> reserve per-bucket runs (1 global
// atomic each) -> write packed (src<<10 | dst&1023). Runs ~42 pairs = 168 B.
__global__ void k_binfill(const void* __restrict__ ei,
                          const int* __restrict__ flag, int E,
                          int* __restrict__ gcur, int* __restrict__ pairs,
                          int NB) {
    __shared__ int h[128];
    __shared__ int cur[128];
    for (int i = threadIdx.x; i < NB; i += 512) h[i] = 0;
    __syncthreads();
    const bool is32 = (*flag != 0);
    long long base = (long long)blockIdx.x * CHUNK_F;
    int lim = (int)min((long long)CHUNK_F, (long long)E - base);
    for (int i = threadIdx.x; i < lim; i += 512) {
        int d = load_dst(ei, is32, E, base + i);
        atomicAdd(&h[d >> SHIFT], 1);
    }
    __syncthreads();
    for (int i = threadIdx.x; i < NB; i += 512)
        cur[i] = h[i] ? atomicAdd(&gcur[i], h[i]) : 0;
    __syncthreads();
    for (int i = threadIdx.x; i < lim; i += 512) {
        int s = load_src(ei, is32, E, base + i);
        int d = load_dst(ei, is32, E, base + i);
        int slot = atomicAdd(&cur[d >> SHIFT], 1);
        pairs[slot] = (int)(((unsigned)s << SHIFT) | (unsigned)(d & (NPB - 1)));
    }
}

// DSPL blocks per bucket (512 threads): LDS histogram of the slice's dst
// rows, flushed NON-atomically to pdeg[blockIdx][1024]. No global atomics.
__global__ void k_deg_part(const int* __restrict__ pairs,
                           const int* __restrict__ bbase,
                           const int* __restrict__ bcnt,
                           int* __restrict__ pdeg) {
    __shared__ int hist[NPB];
    int tid = threadIdx.x;
    for (int j = tid; j < NPB; j += 512) hist[j] = 0;
    __syncthreads();
    int b = blockIdx.x >> 3;
    int s = blockIdx.x & 7;
    int beg = bbase[b], c = bcnt[b];
    int lo = beg + (int)(((long long)c * s) >> 3);
    int hi = beg + (int)(((long long)c * (s + 1)) >> 3);
    for (int i = lo + tid; i < hi; i += 512)
        atomicAdd(&hist[((unsigned)pairs[i]) & (NPB - 1)], 1);
    __syncthreads();
    int* dst = pdeg + (size_t)blockIdx.x * NPB;
    for (int j = tid; j < NPB; j += 512) dst[j] = hist[j];
}

// Per node: deg = sum of DSPL partials; dinv = rsqrt(1+deg);
// y[n] = dinv * (x[n] @ W) packed bf16x2 into 5 u32 words of an 8-word row.
__global__ void k_xw(const float* __restrict__ x, const float* __restrict__ W,
                     const int* __restrict__ pdeg, float* __restrict__ dinv,
                     unsigned* __restrict__ yw, int N) {
    __shared__ float Wt[OUT_CH][IN_CH];
    for (int i = threadIdx.x; i < IN_CH * OUT_CH; i += blockDim.x) {
        int k = i / OUT_CH, c = i - k * OUT_CH;
        Wt[c][k] = W[i];
    }
    __syncthreads();

    int n = blockIdx.x * blockDim.x + threadIdx.x;
    if (n >= N) return;

    float acc[OUT_CH];
#pragma unroll
    for (int c = 0; c < OUT_CH; ++c) acc[c] = 0.0f;

    const float4* xr = (const float4*)(x + (size_t)n * IN_CH);
#pragma unroll 4
    for (int k4 = 0; k4 < IN_CH / 4; ++k4) {
        float4 xv = xr[k4];
#pragma unroll
        for (int c = 0; c < OUT_CH; ++c) {
            float4 wv = *(const float4*)&Wt[c][k4 * 4];
            acc[c] += xv.x * wv.x + xv.y * wv.y + xv.z * wv.z + xv.w * wv.w;
        }
    }

    int b = n >> SHIFT, l = n & (NPB - 1);
    const int* pd = pdeg + ((size_t)b * DSPL) * NPB + l;
    int deg = 0;
#pragma unroll
    for (int s = 0; s < DSPL; ++s) deg += pd[(size_t)s * NPB];
    float d = rsqrtf(1.0f + (float)deg);
    dinv[n] = d;

    uint4 w0;
    w0.x = pk2(d * acc[0], d * acc[1]);
    w0.y = pk2(d * acc[2], d * acc[3]);
    w0.z = pk2(d * acc[4], d * acc[5]);
    w0.w = pk2(d * acc[6], d * acc[7]);
    *(uint4*)(yw + (size_t)n * 8) = w0;
    yw[(size_t)n * 8 + 4] = pk2(d * acc[8], d * acc[9]);
}

// SPLIT blocks per bucket, 512 threads. Per <=4096-pair round: counting-sort
// by the 1024 dst rows in LDS (native int atomics; shfl wave-scan for the
// prefix), then each thread privately accumulates its 2 rows' runs of
// bf16 y[src] gathers in VGPRs. Partials flushed coalesced. No float atomics.
__global__ void k_accum(const int* __restrict__ pairs,
                        const int* __restrict__ bbase,
                        const int* __restrict__ bcnt,
                        const unsigned* __restrict__ yw,
                        float* __restrict__ part, int split_log) {
    __shared__ int hist[NPB];
    __shared__ int base[NPB];
    __shared__ int cur[NPB];
    __shared__ unsigned sorted[CCAP];
    __shared__ int wsums[8];

    int tid = threadIdx.x;
    int lane = tid & 63;
    int wid = tid >> 6;
    int b = blockIdx.x >> split_log;
    int s = blockIdx.x & ((1 << split_log) - 1);
    int beg = bbase[b];
    int c = bcnt[b];
    int lo = beg + (int)(((long long)c * s) >> split_log);
    int hi = beg + (int)(((long long)c * (s + 1)) >> split_log);

    int r0 = tid * 2;  // this thread owns rows r0, r0+1

    float acc[2][OUT_CH];
#pragma unroll
    for (int j = 0; j < 2; ++j)
#pragma unroll
        for (int k = 0; k < OUT_CH; ++k) acc[j][k] = 0.0f;

    for (int clo = lo; clo < hi; clo += CCAP) {
        int m = min(CCAP, hi - clo);

        hist[r0] = 0;
        hist[r0 + 1] = 0;
        __syncthreads();

        // read my <=8 pairs, build row histogram (native int LDS atomics)
        unsigned mine[8];
        int nm = 0;
        for (int i = tid; i < m; i += 512) {
            unsigned pp = (unsigned)pairs[clo + i];
            mine[nm++] = pp;
            atomicAdd(&hist[pp & (NPB - 1)], 1);
        }
        __syncthreads();

        // exclusive scan over 1024 rows: shfl wave-scan + cross-wave fixup
        int lsum = hist[r0] + hist[r0 + 1];
        int incl = lsum;
#pragma unroll
        for (int off = 1; off < 64; off <<= 1) {
            int t = __shfl_up(incl, off);
            if (lane >= off) incl += t;
        }
        if (lane == 63) wsums[wid] = incl;
        __syncthreads();
        int run = incl - lsum;
        for (int w = 0; w < wid; ++w) run += wsums[w];
        base[r0] = run;
        cur[r0] = run;
        run += hist[r0];
        base[r0 + 1] = run;
        cur[r0 + 1] = run;
        __syncthreads();

        // scatter src ids into row-sorted LDS order
        for (int j = 0; j < nm; ++j) {
            unsigned pp = mine[j];
            int slot = atomicAdd(&cur[pp & (NPB - 1)], 1);
            sorted[slot] = pp >> SHIFT;
        }
        __syncthreads();

        // private VGPR accumulation over my 2 rows' contiguous runs
#pragma unroll
        for (int j = 0; j < 2; ++j) {
            int rb = base[r0 + j];
            int rl = hist[r0 + j];
            for (int q = 0; q < rl; ++q) {
                unsigned src = sorted[rb + q];
                const unsigned* yr = yw + (size_t)src * 8;
                uint4 a = *(const uint4*)yr;
                unsigned w4 = yr[4];
                acc[j][0] += lo16(a.x); acc[j][1] += hi16(a.x);
                acc[j][2] += lo16(a.y); acc[j][3] += hi16(a.y);
                acc[j][4] += lo16(a.z); acc[j][5] += hi16(a.z);
                acc[j][6] += lo16(a.w); acc[j][7] += hi16(a.w);
                acc[j][8] += lo16(w4);  acc[j][9] += hi16(w4);
            }
        }
        __syncthreads();  // protect hist/sorted/wsums before next round
    }

    // flush partial: thread writes 80 contiguous bytes (rows r0, r0+1)
    float* dst = part + (size_t)blockIdx.x * (NPB * OUT_CH) +
                 (size_t)r0 * OUT_CH;
#pragma unroll
    for (int j = 0; j < 2; ++j)
#pragma unroll
        for (int k = 0; k < OUT_CH; ++k) dst[j * OUT_CH + k] = acc[j][k];
}

// out[n][ch] = dinv[n] * (sum of SPLIT partials + y[n][ch]) + bias[ch]
__global__ void k_merge(const float* __restrict__ part,
                        const unsigned* __restrict__ yw,
                        const float* __restrict__ dinv,
                        const float* __restrict__ bias,
                        float* __restrict__ out, int N, int split_log) {
    int idx = blockIdx.x * blockDim.x + threadIdx.x;
    if (idx >= N * OUT_CH) return;
    int n = idx / OUT_CH;
    int ch = idx - n * OUT_CH;
    int b = n >> SHIFT;
    int local = (n & (NPB - 1)) * OUT_CH + ch;
    int spl = 1 << split_log;
    size_t bs = (size_t)b << split_log;
    float s = 0.0f;
    for (int q = 0; q < spl; ++q)
        s += part[(bs + q) * (size_t)(NPB * OUT_CH) + local];
    unsigned w = yw[(size_t)n * 8 + (ch >> 1)];
    float yv = (ch & 1) ? hi16(w) : lo16(w);
    out[idx] = dinv[n] * (s + yv) + bias[ch];
}

// ============================================================================
// Fallback path (atomic scatter) — used only if ws too small / N too large
// ============================================================================

__global__ void k_detect_fb(const unsigned int* __restrict__ w, int* flag,
                            int nwords_check) {
    __shared__ int any_nz;
    if (threadIdx.x == 0) any_nz = 0;
    __syncthreads();
    int local = 0;
    for (int i = threadIdx.x; i < nwords_check; i += blockDim.x)
        if (w[2 * i + 1] != 0u) local = 1;
    if (local) atomicOr(&any_nz, 1);
    __syncthreads();
    if (threadIdx.x == 0) *flag = any_nz;
}

__global__ void k_count_fb(const void* __restrict__ ei, int* __restrict__ cnt,
                           const int* __restrict__ flag, int E) {
    const bool is32 = (*flag != 0);
    long long i = (long long)blockIdx.x * blockDim.x + threadIdx.x;
    long long stride = (long long)gridDim.x * blockDim.x;
    for (; i < E; i += stride) atomicAdd(&cnt[load_dst(ei, is32, E, i)], 1);
}

__global__ void k_xw_fb(const float* __restrict__ x,
                        const float* __restrict__ W,
                        const int* __restrict__ cnt, float* __restrict__ dinv,
                        float* __restrict__ y, float* __restrict__ out_seed,
                        int N) {
    __shared__ float Wt[OUT_CH][IN_CH];
    for (int i = threadIdx.x; i < IN_CH * OUT_CH; i += blockDim.x) {
        int k = i / OUT_CH, c = i - k * OUT_CH;
        Wt[c][k] = W[i];
    }
    __syncthreads();
    int n = blockIdx.x * blockDim.x + threadIdx.x;
    if (n >= N) return;
    float acc[OUT_CH];
#pragma unroll
    for (int c = 0; c < OUT_CH; ++c) acc[c] = 0.0f;
    const float4* xr = (const float4*)(x + (size_t)n * IN_CH);
#pragma unroll 4
    for (int k4 = 0; k4 < IN_CH / 4; ++k4) {
        float4 xv = xr[k4];
#pragma unroll
        for (int c = 0; c < OUT_CH; ++c) {
            float4 wv = *(const float4*)&Wt[c][k4 * 4];
            acc[c] += xv.x * wv.x + xv.y * wv.y + xv.z * wv.z + xv.w * wv.w;
        }
    }
    float d = rsqrtf(1.0f + (float)cnt[n]);
    dinv[n] = d;
    float2* yr = (float2*)(y + (size_t)n * OUT_CH);
    float2* orow = (float2*)(out_seed + (size_t)n * OUT_CH);
#pragma unroll
    for (int c2 = 0; c2 < OUT_CH / 2; ++c2) {
        float2 v;
        v.x = d * acc[2 * c2];
        v.y = d * acc[2 * c2 + 1];
        yr[c2] = v;
        orow[c2] = v;
    }
}

__global__ void k_scatter_fb(const void* __restrict__ ei,
                             const float* __restrict__ y,
                             float* __restrict__ out,
                             const int* __restrict__ flag, int E) {
    const bool is32 = (*flag != 0);
    long long i = (long long)blockIdx.x * blockDim.x + threadIdx.x;
    long long stride = (long long)gridDim.x * blockDim.x;
    for (; i < E; i += stride) {
        long long s = load_src(ei, is32, E, i);
        long long t = load_dst(ei, is32, E, i);
        const float2* yr = (const float2*)(y + s * OUT_CH);
        float2 v0 = yr[0], v1 = yr[1], v2 = yr[2], v3 = yr[3], v4 = yr[4];
        float* orow = out + t * OUT_CH;
        atomicAdd(&orow[0], v0.x);
        atomicAdd(&orow[1], v0.y);
        atomicAdd(&orow[2], v1.x);
        atomicAdd(&orow[3], v1.y);
        atomicAdd(&orow[4], v2.x);
        atomicAdd(&orow[5], v2.y);
        atomicAdd(&orow[6], v3.x);
        atomicAdd(&orow[7], v3.y);
        atomicAdd(&orow[8], v4.x);
        atomicAdd(&orow[9], v4.y);
    }
}

__global__ void k_final_fb(const float* __restrict__ dinv,
                           const float* __restrict__ b,
                           float* __restrict__ out, int N) {
    int n = blockIdx.x * blockDim.x + threadIdx.x;
    if (n >= N) return;
    float d = dinv[n];
    float2* orow = (float2*)(out + (size_t)n * OUT_CH);
#pragma unroll
    for (int c2 = 0; c2 < OUT_CH / 2; ++c2) {
        float2 v = orow[c2];
        v.x = v.x * d + b[2 * c2];
        v.y = v.y * d + b[2 * c2 + 1];
        orow[c2] = v;
    }
}

// ============================================================================
// Launch
// ============================================================================

extern "C" void kernel_launch(void* const* d_in, const int* in_sizes, int n_in,
                              void* d_out, int out_size, void* d_ws,
                              size_t ws_size, hipStream_t stream) {
    const float* x = (const float*)d_in[0];
    const void* ei = d_in[1];
    const float* W = (const float*)d_in[2];
    const float* b = (const float*)d_in[3];
    float* out = (float*)d_out;

    int N = in_sizes[0] / IN_CH;  // 100000
    int E = in_sizes[1] / 2;      // 3200000

    int NB = (N + NPB - 1) >> SHIFT;  // buckets (98)
    int nblkN = (N + 255) / 256;
    int nblkC = (E + CHUNK_C - 1) / CHUNK_C;
    int nblkF = (E + CHUNK_F - 1) / CHUNK_F;

    // primary ws layout (4B units):
    //   bcnt[128] | bbase[128] | gcur[128] | flag | pad16 | pdeg[NB*8*1024] |
    //   dinv[N] | pad16 | yw[8N] (32B bf16 rows) | pairs[E] | pad16 |
    //   part[(NB<<sl)*10240]
    size_t off_pdeg = ((size_t)(3 * 128 + 1) + 15) & ~(size_t)15;
    size_t off_dinv = off_pdeg + (size_t)NB * DSPL * NPB;
    size_t off_yw = ((off_dinv + (size_t)N) + 15) & ~(size_t)15;
    size_t off_pairs = off_yw + (size_t)8 * N;
    size_t off_part = ((off_pairs + (size_t)E) + 15) & ~(size_t)15;

    // adaptive split: largest of {8,4,2,1} whose partial buffer fits
    int split_log = -1;
    for (int sl = 3; sl >= 0; --sl) {
        size_t needed = (off_part + ((size_t)NB << sl) * (NPB * OUT_CH)) * 4;
        if (ws_size >= needed) {
            split_log = sl;
            break;
        }
    }

    if (split_log >= 0 && NB <= 128 && N <= (1 << 22)) {
        int* wsi = (int*)d_ws;
        int* bcnt = wsi;
        int* bbase = bcnt + 128;
        int* gcur = bbase + 128;
        int* flag = gcur + 128;
        int* pdeg = wsi + off_pdeg;
        float* dinv = (float*)(wsi + off_dinv);
        unsigned* yw = (unsigned*)(wsi + off_yw);
        int* pairs = wsi + off_pairs;
        float* part = (float*)(wsi + off_part);

        k_init<<<1, 256, 0, stream>>>((const unsigned int*)ei, bcnt, flag, NB,
                                      8192);
        k_bincount<<<nblkC, 256, 0, stream>>>(ei, flag, E, bcnt, NB);
        k_scanNB<<<1, 128, 0, stream>>>(bcnt, bbase, gcur, NB);
        k_binfill<<<nblkF, 512, 0, stream>>>(ei, flag, E, gcur, pairs, NB);
        k_deg_part<<<NB * DSPL, 512, 0, stream>>>(pairs, bbase, bcnt, pdeg);
        k_xw<<<nblkN, 256, 0, stream>>>(x, W, pdeg, dinv, yw, N);
        k_accum<<<NB << split_log, 512, 0, stream>>>(pairs, bbase, bcnt, yw,
                                                     part, split_log);
        int mthreads = N * OUT_CH;
        k_merge<<<(mthreads + 255) / 256, 256, 0, stream>>>(part, yw, dinv, b,
                                                            out, N, split_log);
    } else {
        // -------- fallback: atomic scatter --------
        int* wsi = (int*)d_ws;
        int* cnt = wsi;                     // N
        int* flag = cnt + N;                // 1
        size_t off = ((size_t)N + 2) & ~(size_t)1;
        float* dinv = (float*)(wsi + off);  // N
        float* y = dinv + N;                // 10N

        k_zero_i<<<nblkN, 256, 0, stream>>>(cnt, N);
        k_detect_fb<<<1, 256, 0, stream>>>((const unsigned int*)ei, flag,
                                           8192);
        k_count_fb<<<4096, 256, 0, stream>>>(ei, cnt, flag, E);
        k_xw_fb<<<nblkN, 256, 0, stream>>>(x, W, cnt, dinv, y, out, N);
        k_scatter_fb<<<4096, 256, 0, stream>>>(ei, y, out, flag, E);
        k_final_fb<<<nblkN, 256, 0, stream>>>(dinv, b, out, N);
    }
}

// Round 12
// 116.170 us; speedup vs baseline: 1.3419x; 1.3419x over previous
//
#include <hip/hip_runtime.h>

#define IN_CH 128
#define OUT_CH 10
#define SHIFT 10                   // nodes per bucket = 1024
#define NPB 1024
#define CHUNK_C 2048               // bincount chunk (exact path only)
#define CHUNK_F 4096               // binfill chunk (512 thr, 8 edges/thread)
#define CCAP 2048                  // pairs per counting-sort round in k_accum
#define DSPL 8                     // deg slices per bucket
#define OVFCAP (1 << 20)           // overflow list capacity (edges)

// bf16 helpers (RNE pack, shift unpack)
__device__ __forceinline__ unsigned pk2(float a, float b) {
    unsigned ua = __float_as_uint(a);
    ua = (ua + 0x7fffu + ((ua >> 16) & 1u)) >> 16;
    unsigned ub = __float_as_uint(b);
    ub = (ub + 0x7fffu + ((ub >> 16) & 1u)) >> 16;
    return ua | (ub << 16);
}
__device__ __forceinline__ float lo16(unsigned u) {
    return __uint_as_float(u << 16);
}
__device__ __forceinline__ float hi16(unsigned u) {
    return __uint_as_float(u & 0xffff0000u);
}

__device__ __forceinline__ int load_dst(const void* ei, bool is32, long long E,
                                        long long i) {
    return is32 ? ((const int*)ei)[E + i] : (int)((const long long*)ei)[E + i];
}
__device__ __forceinline__ int load_src(const void* ei, bool is32, long long E,
                                        long long i) {
    return is32 ? ((const int*)ei)[i] : (int)((const long long*)ei)[i];
}

// ============================================================================
// Init kernels
// ============================================================================

// Capacity path: gcur[b]=bbase[b]=b*cap, ovfcnt=0, int64/int32 detect.
__global__ void k_init_cap(const unsigned int* __restrict__ w,
                           int* __restrict__ gcur, int* __restrict__ bbase,
                           int* __restrict__ ovfcnt, int* __restrict__ flag,
                           int NB, int cap, int nwords_check) {
    __shared__ int any_nz;
    int tid = threadIdx.x;
    for (int i = tid; i < NB; i += 256) {
        gcur[i] = i * cap;
        bbase[i] = i * cap;
    }
    if (tid == 0) {
        any_nz = 0;
        *ovfcnt = 0;
    }
    __syncthreads();
    int local = 0;
    for (int i = tid; i < nwords_check; i += 256)
        if (w[2 * i + 1] != 0u) local = 1;
    if (local) atomicOr(&any_nz, 1);
    __syncthreads();
    if (tid == 0) *flag = any_nz;
}

// Exact path: zero bcnt + detect.
__global__ void k_init_exact(const unsigned int* __restrict__ w,
                             int* __restrict__ bcnt, int* __restrict__ flag,
                             int NB, int nwords_check) {
    __shared__ int any_nz;
    for (int i = threadIdx.x; i < NB; i += 256) bcnt[i] = 0;
    if (threadIdx.x == 0) any_nz = 0;
    __syncthreads();
    int local = 0;
    for (int i = threadIdx.x; i < nwords_check; i += 256)
        if (w[2 * i + 1] != 0u) local = 1;
    if (local) atomicOr(&any_nz, 1);
    __syncthreads();
    if (threadIdx.x == 0) *flag = any_nz;
}

__global__ void k_zero_i(int* __restrict__ p, int n) {
    int i = blockIdx.x * blockDim.x + threadIdx.x;
    int stride = gridDim.x * blockDim.x;
    for (; i < n; i += stride) p[i] = 0;
}

// ============================================================================
// Exact-count helpers (used only when ws can't fit capacity slack)
// ============================================================================

__global__ void k_bincount(const void* __restrict__ ei,
                           const int* __restrict__ flag, int E,
                           int* __restrict__ bcnt, int NB) {
    __shared__ int h[128];
    for (int i = threadIdx.x; i < NB; i += blockDim.x) h[i] = 0;
    __syncthreads();
    const bool is32 = (*flag != 0);
    long long base = (long long)blockIdx.x * CHUNK_C;
    int lim = (int)min((long long)CHUNK_C, (long long)E - base);
    for (int i = threadIdx.x; i < lim; i += blockDim.x) {
        int d = load_dst(ei, is32, E, base + i);
        atomicAdd(&h[d >> SHIFT], 1);
    }
    __syncthreads();
    for (int i = threadIdx.x; i < NB; i += blockDim.x)
        if (h[i]) atomicAdd(&bcnt[i], h[i]);
}

__global__ void k_scanNB(const int* __restrict__ bcnt, int* __restrict__ bbase,
                         int* __restrict__ gcur, int NB) {
    __shared__ int s[128];
    int tid = threadIdx.x;
    int v = (tid < NB) ? bcnt[tid] : 0;
    if (tid < 128) s[tid] = v;
    __syncthreads();
    for (int off = 1; off < 128; off <<= 1) {
        int t = (tid < 128 && tid >= off) ? s[tid - off] : 0;
        __syncthreads();
        if (tid < 128) s[tid] += t;
        __syncthreads();
    }
    if (tid < NB) {
        int e = s[tid] - v;
        bbase[tid] = e;
        gcur[tid] = e;
    }
}

// ============================================================================
// Binfill: register-cached edges, one global-memory pass.
// cap>0: capacity-bounded segments + overflow list. cap==0: exact segments.
// ============================================================================

__global__ void k_binfill(const void* __restrict__ ei,
                          const int* __restrict__ flag, int E,
                          int* __restrict__ gcur, int* __restrict__ pairs,
                          int NB, int cap, int2* __restrict__ ovf,
                          int* __restrict__ ovfcnt) {
    __shared__ int h[128];
    __shared__ int cur[128];
    int tid = threadIdx.x;
    for (int i = tid; i < NB; i += 512) h[i] = 0;
    __syncthreads();
    const bool is32 = (*flag != 0);
    long long base = (long long)blockIdx.x * CHUNK_F;
    int lim = (int)min((long long)CHUNK_F, (long long)E - base);

    int ss[8], dd[8];
#pragma unroll
    for (int j = 0; j < 8; ++j) {
        int i = tid + j * 512;
        if (i < lim) {
            ss[j] = load_src(ei, is32, E, base + i);
            dd[j] = load_dst(ei, is32, E, base + i);
        }
    }
#pragma unroll
    for (int j = 0; j < 8; ++j) {
        int i = tid + j * 512;
        if (i < lim) atomicAdd(&h[dd[j] >> SHIFT], 1);
    }
    __syncthreads();
    for (int i = tid; i < NB; i += 512)
        cur[i] = h[i] ? atomicAdd(&gcur[i], h[i]) : 0;
    __syncthreads();
#pragma unroll
    for (int j = 0; j < 8; ++j) {
        int i = tid + j * 512;
        if (i < lim) {
            int bk = dd[j] >> SHIFT;
            int slot = atomicAdd(&cur[bk], 1);
            if (cap > 0 && slot >= (bk + 1) * cap) {
                int o = atomicAdd(ovfcnt, 1);
                if (o < OVFCAP) {
                    ovf[o].x = ss[j];
                    ovf[o].y = dd[j];
                }
            } else {
                pairs[slot] = (int)(((unsigned)ss[j] << SHIFT) |
                                    (unsigned)(dd[j] & (NPB - 1)));
            }
        }
    }
}

// Capacity path: derive bcnt from final cursors.
__global__ void k_fin(const int* __restrict__ gcur, int* __restrict__ bcnt,
                      int NB, int cap) {
    int i = threadIdx.x;
    if (i < NB) {
        int c = gcur[i] - i * cap;
        bcnt[i] = c > cap ? cap : c;
    }
}

// ============================================================================
// Degree, XW, accumulate, merge
// ============================================================================

// DSPL blocks per bucket (512 threads): LDS hist of the slice's dst rows,
// flushed NON-atomically to pdeg[blockIdx][1024]. No global atomics.
__global__ void k_deg_part(const int* __restrict__ pairs,
                           const int* __restrict__ bbase,
                           const int* __restrict__ bcnt,
                           int* __restrict__ pdeg) {
    __shared__ int hist[NPB];
    int tid = threadIdx.x;
    for (int j = tid; j < NPB; j += 512) hist[j] = 0;
    __syncthreads();
    int b = blockIdx.x >> 3;
    int s = blockIdx.x & 7;
    int beg = bbase[b], c = bcnt[b];
    int lo = beg + (int)(((long long)c * s) >> 3);
    int hi = beg + (int)(((long long)c * (s + 1)) >> 3);
    for (int i = lo + tid; i < hi; i += 512)
        atomicAdd(&hist[((unsigned)pairs[i]) & (NPB - 1)], 1);
    __syncthreads();
    int* dst = pdeg + (size_t)blockIdx.x * NPB;
    for (int j = tid; j < NPB; j += 512) dst[j] = hist[j];
}

// Overflow edges' degree contribution: atomically add into pdeg slice 0 of
// the dst's bucket (runs AFTER k_deg_part overwrites pdeg, BEFORE k_xw).
__global__ void k_ovf_deg(const int2* __restrict__ ovf,
                          const int* __restrict__ ovfcnt,
                          int* __restrict__ pdeg) {
    int cnt = *ovfcnt;
    if (cnt > OVFCAP) cnt = OVFCAP;
    int stride = gridDim.x * blockDim.x;
    for (int i = blockIdx.x * blockDim.x + threadIdx.x; i < cnt; i += stride) {
        int d = ovf[i].y;
        int b = d >> SHIFT;
        atomicAdd(&pdeg[((size_t)b * DSPL) * NPB + (d & (NPB - 1))], 1);
    }
}

// Per node: deg = sum of DSPL partials; dinv = rsqrt(1+deg);
// y[n] = dinv * (x[n] @ W) packed bf16x2 into 5 u32 words of an 8-word row.
__global__ void k_xw(const float* __restrict__ x, const float* __restrict__ W,
                     const int* __restrict__ pdeg, float* __restrict__ dinv,
                     unsigned* __restrict__ yw, int N) {
    __shared__ float Wt[OUT_CH][IN_CH];
    for (int i = threadIdx.x; i < IN_CH * OUT_CH; i += blockDim.x) {
        int k = i / OUT_CH, c = i - k * OUT_CH;
        Wt[c][k] = W[i];
    }
    __syncthreads();

    int n = blockIdx.x * blockDim.x + threadIdx.x;
    if (n >= N) return;

    float acc[OUT_CH];
#pragma unroll
    for (int c = 0; c < OUT_CH; ++c) acc[c] = 0.0f;

    const float4* xr = (const float4*)(x + (size_t)n * IN_CH);
#pragma unroll 4
    for (int k4 = 0; k4 < IN_CH / 4; ++k4) {
        float4 xv = xr[k4];
#pragma unroll
        for (int c = 0; c < OUT_CH; ++c) {
            float4 wv = *(const float4*)&Wt[c][k4 * 4];
            acc[c] += xv.x * wv.x + xv.y * wv.y + xv.z * wv.z + xv.w * wv.w;
        }
    }

    int b = n >> SHIFT, l = n & (NPB - 1);
    const int* pd = pdeg + ((size_t)b * DSPL) * NPB + l;
    int deg = 0;
#pragma unroll
    for (int s = 0; s < DSPL; ++s) deg += pd[(size_t)s * NPB];
    float d = rsqrtf(1.0f + (float)deg);
    dinv[n] = d;

    uint4 w0;
    w0.x = pk2(d * acc[0], d * acc[1]);
    w0.y = pk2(d * acc[2], d * acc[3]);
    w0.z = pk2(d * acc[4], d * acc[5]);
    w0.w = pk2(d * acc[6], d * acc[7]);
    *(uint4*)(yw + (size_t)n * 8) = w0;
    yw[(size_t)n * 8 + 4] = pk2(d * acc[8], d * acc[9]);
}

// 8 blocks per bucket, 512 threads, CCAP 2048 (round-10 measured-best).
// Counting-sort the slice's pairs by dst row in LDS (int atomics; shfl
// wave-scan prefix), then each thread accumulates its 2 rows' runs of bf16
// y[src] gathers in VGPRs. Partials flushed coalesced. No float atomics.
__global__ void k_accum(const int* __restrict__ pairs,
                        const int* __restrict__ bbase,
                        const int* __restrict__ bcnt,
                        const unsigned* __restrict__ yw,
                        float* __restrict__ part) {
    __shared__ int hist[NPB];
    __shared__ int base[NPB];
    __shared__ int cur[NPB];
    __shared__ unsigned sorted[CCAP];
    __shared__ int wsums[8];

    int tid = threadIdx.x;
    int lane = tid & 63;
    int wid = tid >> 6;
    int b = blockIdx.x >> 3;
    int s = blockIdx.x & 7;
    int beg = bbase[b];
    int c = bcnt[b];
    int lo = beg + (int)(((long long)c * s) >> 3);
    int hi = beg + (int)(((long long)c * (s + 1)) >> 3);

    int r0 = tid * 2;  // this thread owns rows r0, r0+1

    float acc[2][OUT_CH];
#pragma unroll
    for (int j = 0; j < 2; ++j)
#pragma unroll
        for (int k = 0; k < OUT_CH; ++k) acc[j][k] = 0.0f;

    for (int clo = lo; clo < hi; clo += CCAP) {
        int m = min(CCAP, hi - clo);

        hist[r0] = 0;
        hist[r0 + 1] = 0;
        __syncthreads();

        // read my <=4 pairs (static unroll), build row histogram
        unsigned mine[4];
#pragma unroll
        for (int j = 0; j < 4; ++j) {
            int i = tid + j * 512;
            if (i < m) {
                unsigned pp = (unsigned)pairs[clo + i];
                mine[j] = pp;
                atomicAdd(&hist[pp & (NPB - 1)], 1);
            }
        }
        __syncthreads();

        // exclusive scan over 1024 rows: shfl wave-scan + cross-wave fixup
        int lsum = hist[r0] + hist[r0 + 1];
        int incl = lsum;
#pragma unroll
        for (int off = 1; off < 64; off <<= 1) {
            int t = __shfl_up(incl, off);
            if (lane >= off) incl += t;
        }
        if (lane == 63) wsums[wid] = incl;
        __syncthreads();
        int run = incl - lsum;
        for (int w = 0; w < wid; ++w) run += wsums[w];
        base[r0] = run;
        cur[r0] = run;
        run += hist[r0];
        base[r0 + 1] = run;
        cur[r0 + 1] = run;
        __syncthreads();

        // scatter src ids into row-sorted LDS order
#pragma unroll
        for (int j = 0; j < 4; ++j) {
            int i = tid + j * 512;
            if (i < m) {
                unsigned pp = mine[j];
                int slot = atomicAdd(&cur[pp & (NPB - 1)], 1);
                sorted[slot] = pp >> SHIFT;
            }
        }
        __syncthreads();

        // private VGPR accumulation over my 2 rows' contiguous runs
#pragma unroll
        for (int j = 0; j < 2; ++j) {
            int rb = base[r0 + j];
            int rl = hist[r0 + j];
            for (int q = 0; q < rl; ++q) {
                unsigned src = sorted[rb + q];
                const unsigned* yr = yw + (size_t)src * 8;
                uint4 a = *(const uint4*)yr;
                unsigned w4 = yr[4];
                acc[j][0] += lo16(a.x); acc[j][1] += hi16(a.x);
                acc[j][2] += lo16(a.y); acc[j][3] += hi16(a.y);
                acc[j][4] += lo16(a.z); acc[j][5] += hi16(a.z);
                acc[j][6] += lo16(a.w); acc[j][7] += hi16(a.w);
                acc[j][8] += lo16(w4);  acc[j][9] += hi16(w4);
            }
        }
        __syncthreads();  // protect hist/sorted/wsums before next round
    }

    // flush partial: thread writes 80 contiguous bytes (rows r0, r0+1)
    float* dst = part + (size_t)blockIdx.x * (NPB * OUT_CH) +
                 (size_t)r0 * OUT_CH;
#pragma unroll
    for (int j = 0; j < 2; ++j)
#pragma unroll
        for (int k = 0; k < OUT_CH; ++k) dst[j * OUT_CH + k] = acc[j][k];
}

// out[n][ch] = dinv[n] * (sum of 8 partials + y[n][ch]) + bias[ch]
__global__ void k_merge(const float* __restrict__ part,
                        const unsigned* __restrict__ yw,
                        const float* __restrict__ dinv,
                        const float* __restrict__ bias,
                        float* __restrict__ out, int N) {
    int idx = blockIdx.x * blockDim.x + threadIdx.x;
    if (idx >= N * OUT_CH) return;
    int n = idx / OUT_CH;
    int ch = idx - n * OUT_CH;
    int b = n >> SHIFT;
    int local = (n & (NPB - 1)) * OUT_CH + ch;
    size_t bs = (size_t)b << 3;
    float s = 0.0f;
#pragma unroll
    for (int q = 0; q < 8; ++q)
        s += part[(bs + q) * (size_t)(NPB * OUT_CH) + local];
    unsigned w = yw[(size_t)n * 8 + (ch >> 1)];
    float yv = (ch & 1) ? hi16(w) : lo16(w);
    out[idx] = dinv[n] * (s + yv) + bias[ch];
}

// Overflow edges' messages: out[d][:] += dinv[d] * y[s][:] (after merge).
__global__ void k_ovf_msg(const int2* __restrict__ ovf,
                          const int* __restrict__ ovfcnt,
                          const unsigned* __restrict__ yw,
                          const float* __restrict__ dinv,
                          float* __restrict__ out) {
    int cnt = *ovfcnt;
    if (cnt > OVFCAP) cnt = OVFCAP;
    int stride = gridDim.x * blockDim.x;
    for (int i = blockIdx.x * blockDim.x + threadIdx.x; i < cnt; i += stride) {
        int s = ovf[i].x;
        int d = ovf[i].y;
        float dn = dinv[d];
        const unsigned* yr = yw + (size_t)s * 8;
        uint4 a = *(const uint4*)yr;
        unsigned w4 = yr[4];
        float* orow = out + (size_t)d * OUT_CH;
        atomicAdd(&orow[0], dn * lo16(a.x));
        atomicAdd(&orow[1], dn * hi16(a.x));
        atomicAdd(&orow[2], dn * lo16(a.y));
        atomicAdd(&orow[3], dn * hi16(a.y));
        atomicAdd(&orow[4], dn * lo16(a.z));
        atomicAdd(&orow[5], dn * hi16(a.z));
        atomicAdd(&orow[6], dn * lo16(a.w));
        atomicAdd(&orow[7], dn * hi16(a.w));
        atomicAdd(&orow[8], dn * lo16(w4));
        atomicAdd(&orow[9], dn * hi16(w4));
    }
}

// ============================================================================
// Fallback path (atomic scatter) — used only if ws too small / N too large
// ============================================================================

__global__ void k_detect_fb(const unsigned int* __restrict__ w, int* flag,
                            int nwords_check) {
    __shared__ int any_nz;
    if (threadIdx.x == 0) any_nz = 0;
    __syncthreads();
    int local = 0;
    for (int i = threadIdx.x; i < nwords_check; i += blockDim.x)
        if (w[2 * i + 1] != 0u) local = 1;
    if (local) atomicOr(&any_nz, 1);
    __syncthreads();
    if (threadIdx.x == 0) *flag = any_nz;
}

__global__ void k_count_fb(const void* __restrict__ ei, int* __restrict__ cnt,
                           const int* __restrict__ flag, int E) {
    const bool is32 = (*flag != 0);
    long long i = (long long)blockIdx.x * blockDim.x + threadIdx.x;
    long long stride = (long long)gridDim.x * blockDim.x;
    for (; i < E; i += stride) atomicAdd(&cnt[load_dst(ei, is32, E, i)], 1);
}

__global__ void k_xw_fb(const float* __restrict__ x,
                        const float* __restrict__ W,
                        const int* __restrict__ cnt, float* __restrict__ dinv,
                        float* __restrict__ y, float* __restrict__ out_seed,
                        int N) {
    __shared__ float Wt[OUT_CH][IN_CH];
    for (int i = threadIdx.x; i < IN_CH * OUT_CH; i += blockDim.x) {
        int k = i / OUT_CH, c = i - k * OUT_CH;
        Wt[c][k] = W[i];
    }
    __syncthreads();
    int n = blockIdx.x * blockDim.x + threadIdx.x;
    if (n >= N) return;
    float acc[OUT_CH];
#pragma unroll
    for (int c = 0; c < OUT_CH; ++c) acc[c] = 0.0f;
    const float4* xr = (const float4*)(x + (size_t)n * IN_CH);
#pragma unroll 4
    for (int k4 = 0; k4 < IN_CH / 4; ++k4) {
        float4 xv = xr[k4];
#pragma unroll
        for (int c = 0; c < OUT_CH; ++c) {
            float4 wv = *(const float4*)&Wt[c][k4 * 4];
            acc[c] += xv.x * wv.x + xv.y * wv.y + xv.z * wv.z + xv.w * wv.w;
        }
    }
    float d = rsqrtf(1.0f + (float)cnt[n]);
    dinv[n] = d;
    float2* yr = (float2*)(y + (size_t)n * OUT_CH);
    float2* orow = (float2*)(out_seed + (size_t)n * OUT_CH);
#pragma unroll
    for (int c2 = 0; c2 < OUT_CH / 2; ++c2) {
        float2 v;
        v.x = d * acc[2 * c2];
        v.y = d * acc[2 * c2 + 1];
        yr[c2] = v;
        orow[c2] = v;
    }
}

__global__ void k_scatter_fb(const void* __restrict__ ei,
                             const float* __restrict__ y,
                             float* __restrict__ out,
                             const int* __restrict__ flag, int E) {
    const bool is32 = (*flag != 0);
    long long i = (long long)blockIdx.x * blockDim.x + threadIdx.x;
    long long stride = (long long)gridDim.x * blockDim.x;
    for (; i < E; i += stride) {
        long long s = load_src(ei, is32, E, i);
        long long t = load_dst(ei, is32, E, i);
        const float2* yr = (const float2*)(y + s * OUT_CH);
        float2 v0 = yr[0], v1 = yr[1], v2 = yr[2], v3 = yr[3], v4 = yr[4];
        float* orow = out + t * OUT_CH;
        atomicAdd(&orow[0], v0.x);
        atomicAdd(&orow[1], v0.y);
        atomicAdd(&orow[2], v1.x);
        atomicAdd(&orow[3], v1.y);
        atomicAdd(&orow[4], v2.x);
        atomicAdd(&orow[5], v2.y);
        atomicAdd(&orow[6], v3.x);
        atomicAdd(&orow[7], v3.y);
        atomicAdd(&orow[8], v4.x);
        atomicAdd(&orow[9], v4.y);
    }
}

__global__ void k_final_fb(const float* __restrict__ dinv,
                           const float* __restrict__ b,
                           float* __restrict__ out, int N) {
    int n = blockIdx.x * blockDim.x + threadIdx.x;
    if (n >= N) return;
    float d = dinv[n];
    float2* orow = (float2*)(out + (size_t)n * OUT_CH);
#pragma unroll
    for (int c2 = 0; c2 < OUT_CH / 2; ++c2) {
        float2 v = orow[c2];
        v.x = v.x * d + b[2 * c2];
        v.y = v.y * d + b[2 * c2 + 1];
        orow[c2] = v;
    }
}

// ============================================================================
// Launch
// ============================================================================

extern "C" void kernel_launch(void* const* d_in, const int* in_sizes, int n_in,
                              void* d_out, int out_size, void* d_ws,
                              size_t ws_size, hipStream_t stream) {
    const float* x = (const float*)d_in[0];
    const void* ei = d_in[1];
    const float* W = (const float*)d_in[2];
    const float* b = (const float*)d_in[3];
    float* out = (float*)d_out;

    int N = in_sizes[0] / IN_CH;  // 100000
    int E = in_sizes[1] / 2;      // 3200000

    int NB = (N + NPB - 1) >> SHIFT;  // buckets (98)
    int nblkN = (N + 255) / 256;
    int nblkC = (E + CHUNK_C - 1) / CHUNK_C;
    int nblkF = (E + CHUNK_F - 1) / CHUNK_F;

    // capacity per bucket: mean + 25% + 1024, rounded up to 16
    int cap = (E + NB - 1) / NB;
    cap += cap / 4 + 1024;
    cap = (cap + 15) & ~15;

    // common header (4B units): gcur[128]|bbase[128]|bcnt[128]|flag|ovfcnt
    size_t off_pdeg = 400;
    size_t off_dinv = off_pdeg + (size_t)NB * DSPL * NPB;
    size_t off_yw = (off_dinv + (size_t)N + 15) & ~(size_t)15;
    size_t off_pairs = off_yw + (size_t)8 * N;
    // capacity path
    size_t off_ovf = (off_pairs + (size_t)NB * cap + 15) & ~(size_t)15;
    size_t off_part_c = (off_ovf + (size_t)2 * OVFCAP + 15) & ~(size_t)15;
    size_t needed_c = (off_part_c + ((size_t)NB << 3) * (NPB * OUT_CH)) * 4;
    // exact path
    size_t off_part_e = (off_pairs + (size_t)E + 15) & ~(size_t)15;
    size_t needed_e = (off_part_e + ((size_t)NB << 3) * (NPB * OUT_CH)) * 4;

    bool ok_shape = (NB <= 128) && (N <= (1 << 22));

    if (ok_shape && (ws_size >= needed_c || ws_size >= needed_e)) {
        bool use_cap = (ws_size >= needed_c);
        int* wsi = (int*)d_ws;
        int* gcur = wsi;
        int* bbase = wsi + 128;
        int* bcnt = wsi + 256;
        int* flag = wsi + 384;
        int* ovfcnt = wsi + 385;
        int* pdeg = wsi + off_pdeg;
        float* dinv = (float*)(wsi + off_dinv);
        unsigned* yw = (unsigned*)(wsi + off_yw);
        int* pairs = wsi + off_pairs;
        int2* ovf = (int2*)(wsi + off_ovf);
        float* part = (float*)(wsi + (use_cap ? off_part_c : off_part_e));

        if (use_cap) {
            k_init_cap<<<1, 256, 0, stream>>>((const unsigned int*)ei, gcur,
                                              bbase, ovfcnt, flag, NB, cap,
                                              8192);
            k_binfill<<<nblkF, 512, 0, stream>>>(ei, flag, E, gcur, pairs, NB,
                                                 cap, ovf, ovfcnt);
            k_fin<<<1, 128, 0, stream>>>(gcur, bcnt, NB, cap);
            k_deg_part<<<NB * DSPL, 512, 0, stream>>>(pairs, bbase, bcnt,
                                                      pdeg);
            k_ovf_deg<<<32, 256, 0, stream>>>(ovf, ovfcnt, pdeg);
            k_xw<<<nblkN, 256, 0, stream>>>(x, W, pdeg, dinv, yw, N);
            k_accum<<<NB << 3, 512, 0, stream>>>(pairs, bbase, bcnt, yw, part);
            int mthreads = N * OUT_CH;
            k_merge<<<(mthreads + 255) / 256, 256, 0, stream>>>(part, yw, dinv,
                                                                b, out, N);
            k_ovf_msg<<<32, 256, 0, stream>>>(ovf, ovfcnt, yw, dinv, out);
        } else {
            k_init_exact<<<1, 256, 0, stream>>>((const unsigned int*)ei, bcnt,
                                                flag, NB, 8192);
            k_bincount<<<nblkC, 256, 0, stream>>>(ei, flag, E, bcnt, NB);
            k_scanNB<<<1, 128, 0, stream>>>(bcnt, bbase, gcur, NB);
            k_binfill<<<nblkF, 512, 0, stream>>>(ei, flag, E, gcur, pairs, NB,
                                                 0, nullptr, nullptr);
            k_deg_part<<<NB * DSPL, 512, 0, stream>>>(pairs, bbase, bcnt,
                                                      pdeg);
            k_xw<<<nblkN, 256, 0, stream>>>(x, W, pdeg, dinv, yw, N);
            k_accum<<<NB << 3, 512, 0, stream>>>(pairs, bbase, bcnt, yw, part);
            int mthreads = N * OUT_CH;
            k_merge<<<(mthreads + 255) / 256, 256, 0, stream>>>(part, yw, dinv,
                                                                b, out, N);
        }
    } else {
        // -------- fallback: atomic scatter --------
        int* wsi = (int*)d_ws;
        int* cnt = wsi;                     // N
        int* flag = cnt + N;                // 1
        size_t off = ((size_t)N + 2) & ~(size_t)1;
        float* dinv = (float*)(wsi + off);  // N
        float* y = dinv + N;                // 10N

        k_zero_i<<<nblkN, 256, 0, stream>>>(cnt, N);
        k_detect_fb<<<1, 256, 0, stream>>>((const unsigned int*)ei, flag,
                                           8192);
        k_count_fb<<<4096, 256, 0, stream>>>(ei, cnt, flag, E);
        k_xw_fb<<<nblkN, 256, 0, stream>>>(x, W, cnt, dinv, y, out, N);
        k_scatter_fb<<<4096, 256, 0, stream>>>(ei, y, out, flag, E);
        k_final_fb<<<nblkN, 256, 0, stream>>>(dinv, b, out, N);
    }
}

// Round 13
// 111.099 us; speedup vs baseline: 1.4031x; 1.0456x over previous
//
#include <hip/hip_runtime.h>

#define IN_CH 128
#define OUT_CH 10
#define SHIFT 10                   // nodes per bucket = 1024
#define NPB 1024
#define CHUNK_C 2048               // bincount chunk (exact path only)
#define CHUNK_F 4096               // binfill chunk (512 thr, 8 edges/thread)
#define CCAP 2048                  // pairs per counting-sort round in k_accum
#define DSPL 8                     // deg slices per bucket
#define OVFCAP (1 << 20)           // overflow list capacity (edges)

// bf16 helpers (RNE pack, shift unpack)
__device__ __forceinline__ unsigned pk2(float a, float b) {
    unsigned ua = __float_as_uint(a);
    ua = (ua + 0x7fffu + ((ua >> 16) & 1u)) >> 16;
    unsigned ub = __float_as_uint(b);
    ub = (ub + 0x7fffu + ((ub >> 16) & 1u)) >> 16;
    return ua | (ub << 16);
}
__device__ __forceinline__ float lo16(unsigned u) {
    return __uint_as_float(u << 16);
}
__device__ __forceinline__ float hi16(unsigned u) {
    return __uint_as_float(u & 0xffff0000u);
}

__device__ __forceinline__ int load_dst(const void* ei, bool is32, long long E,
                                        long long i) {
    return is32 ? ((const int*)ei)[E + i] : (int)((const long long*)ei)[E + i];
}
__device__ __forceinline__ int load_src(const void* ei, bool is32, long long E,
                                        long long i) {
    return is32 ? ((const int*)ei)[i] : (int)((const long long*)ei)[i];
}

// ============================================================================
// Init kernels
// ============================================================================

// Capacity path: gcur[b]=bbase[b]=b*cap, ovfcnt=0, int64/int32 detect.
__global__ void k_init_cap(const unsigned int* __restrict__ w,
                           int* __restrict__ gcur, int* __restrict__ bbase,
                           int* __restrict__ ovfcnt, int* __restrict__ flag,
                           int NB, int cap, int nwords_check) {
    __shared__ int any_nz;
    int tid = threadIdx.x;
    for (int i = tid; i < NB; i += 256) {
        gcur[i] = i * cap;
        bbase[i] = i * cap;
    }
    if (tid == 0) {
        any_nz = 0;
        *ovfcnt = 0;
    }
    __syncthreads();
    int local = 0;
    for (int i = tid; i < nwords_check; i += 256)
        if (w[2 * i + 1] != 0u) local = 1;
    if (local) atomicOr(&any_nz, 1);
    __syncthreads();
    if (tid == 0) *flag = any_nz;
}

// Exact path: zero bcnt + detect.
__global__ void k_init_exact(const unsigned int* __restrict__ w,
                             int* __restrict__ bcnt, int* __restrict__ flag,
                             int NB, int nwords_check) {
    __shared__ int any_nz;
    for (int i = threadIdx.x; i < NB; i += 256) bcnt[i] = 0;
    if (threadIdx.x == 0) any_nz = 0;
    __syncthreads();
    int local = 0;
    for (int i = threadIdx.x; i < nwords_check; i += 256)
        if (w[2 * i + 1] != 0u) local = 1;
    if (local) atomicOr(&any_nz, 1);
    __syncthreads();
    if (threadIdx.x == 0) *flag = any_nz;
}

__global__ void k_zero_i(int* __restrict__ p, int n) {
    int i = blockIdx.x * blockDim.x + threadIdx.x;
    int stride = gridDim.x * blockDim.x;
    for (; i < n; i += stride) p[i] = 0;
}

// ============================================================================
// Exact-count helpers (used only when ws can't fit capacity slack)
// ============================================================================

__global__ void k_bincount(const void* __restrict__ ei,
                           const int* __restrict__ flag, int E,
                           int* __restrict__ bcnt, int NB) {
    __shared__ int h[128];
    for (int i = threadIdx.x; i < NB; i += blockDim.x) h[i] = 0;
    __syncthreads();
    const bool is32 = (*flag != 0);
    long long base = (long long)blockIdx.x * CHUNK_C;
    int lim = (int)min((long long)CHUNK_C, (long long)E - base);
    for (int i = threadIdx.x; i < lim; i += blockDim.x) {
        int d = load_dst(ei, is32, E, base + i);
        atomicAdd(&h[d >> SHIFT], 1);
    }
    __syncthreads();
    for (int i = threadIdx.x; i < NB; i += blockDim.x)
        if (h[i]) atomicAdd(&bcnt[i], h[i]);
}

// Exclusive scan -> bbase, gcur. (After binfill, gcur-bbase == count.)
__global__ void k_scanNB(const int* __restrict__ bcnt, int* __restrict__ bbase,
                         int* __restrict__ gcur, int NB) {
    __shared__ int s[128];
    int tid = threadIdx.x;
    int v = (tid < NB) ? bcnt[tid] : 0;
    if (tid < 128) s[tid] = v;
    __syncthreads();
    for (int off = 1; off < 128; off <<= 1) {
        int t = (tid < 128 && tid >= off) ? s[tid - off] : 0;
        __syncthreads();
        if (tid < 128) s[tid] += t;
        __syncthreads();
    }
    if (tid < NB) {
        int e = s[tid] - v;
        bbase[tid] = e;
        gcur[tid] = e;
    }
}

// ============================================================================
// Binfill: register-cached edges, one global-memory pass.
// cap>0: capacity-bounded segments + overflow list. cap==0: exact segments.
// ============================================================================

__global__ void k_binfill(const void* __restrict__ ei,
                          const int* __restrict__ flag, int E,
                          int* __restrict__ gcur, int* __restrict__ pairs,
                          int NB, int cap, int2* __restrict__ ovf,
                          int* __restrict__ ovfcnt) {
    __shared__ int h[128];
    __shared__ int cur[128];
    int tid = threadIdx.x;
    for (int i = tid; i < NB; i += 512) h[i] = 0;
    __syncthreads();
    const bool is32 = (*flag != 0);
    long long base = (long long)blockIdx.x * CHUNK_F;
    int lim = (int)min((long long)CHUNK_F, (long long)E - base);

    int ss[8], dd[8];
#pragma unroll
    for (int j = 0; j < 8; ++j) {
        int i = tid + j * 512;
        if (i < lim) {
            ss[j] = load_src(ei, is32, E, base + i);
            dd[j] = load_dst(ei, is32, E, base + i);
        }
    }
#pragma unroll
    for (int j = 0; j < 8; ++j) {
        int i = tid + j * 512;
        if (i < lim) atomicAdd(&h[dd[j] >> SHIFT], 1);
    }
    __syncthreads();
    for (int i = tid; i < NB; i += 512)
        cur[i] = h[i] ? atomicAdd(&gcur[i], h[i]) : 0;
    __syncthreads();
#pragma unroll
    for (int j = 0; j < 8; ++j) {
        int i = tid + j * 512;
        if (i < lim) {
            int bk = dd[j] >> SHIFT;
            int slot = atomicAdd(&cur[bk], 1);
            if (cap > 0 && slot >= (bk + 1) * cap) {
                int o = atomicAdd(ovfcnt, 1);
                if (o < OVFCAP) {
                    ovf[o].x = ss[j];
                    ovf[o].y = dd[j];
                }
            } else {
                pairs[slot] = (int)(((unsigned)ss[j] << SHIFT) |
                                    (unsigned)(dd[j] & (NPB - 1)));
            }
        }
    }
}

// bucket count from cursors: c = gcur[b]-bbase[b], clamped to cap if cap>0
__device__ __forceinline__ int bucket_cnt(const int* gcur, const int* bbase,
                                          int b, int cap) {
    int c = gcur[b] - bbase[b];
    if (cap > 0 && c > cap) c = cap;
    return c;
}

// ============================================================================
// Degree, XW, accumulate, merge
// ============================================================================

// DSPL blocks per bucket (512 threads): LDS hist of the slice's dst rows,
// flushed NON-atomically to pdeg[blockIdx][1024]. No global atomics.
__global__ void k_deg_part(const int* __restrict__ pairs,
                           const int* __restrict__ bbase,
                           const int* __restrict__ gcur,
                           int* __restrict__ pdeg, int cap) {
    __shared__ int hist[NPB];
    int tid = threadIdx.x;
    for (int j = tid; j < NPB; j += 512) hist[j] = 0;
    __syncthreads();
    int b = blockIdx.x >> 3;
    int s = blockIdx.x & 7;
    int beg = bbase[b];
    int c = bucket_cnt(gcur, bbase, b, cap);
    int lo = beg + (int)(((long long)c * s) >> 3);
    int hi = beg + (int)(((long long)c * (s + 1)) >> 3);
    for (int i = lo + tid; i < hi; i += 512)
        atomicAdd(&hist[((unsigned)pairs[i]) & (NPB - 1)], 1);
    __syncthreads();
    int* dst = pdeg + (size_t)blockIdx.x * NPB;
    for (int j = tid; j < NPB; j += 512) dst[j] = hist[j];
}

// Overflow edges' degree contribution: atomic into pdeg slice 0 (after
// k_deg_part, before k_xw).
__global__ void k_ovf_deg(const int2* __restrict__ ovf,
                          const int* __restrict__ ovfcnt,
                          int* __restrict__ pdeg) {
    int cnt = *ovfcnt;
    if (cnt > OVFCAP) cnt = OVFCAP;
    int stride = gridDim.x * blockDim.x;
    for (int i = blockIdx.x * blockDim.x + threadIdx.x; i < cnt; i += stride) {
        int d = ovf[i].y;
        int b = d >> SHIFT;
        atomicAdd(&pdeg[((size_t)b * DSPL) * NPB + (d & (NPB - 1))], 1);
    }
}

// Per node: deg = sum of DSPL partials; dinv = rsqrt(1+deg);
// y[n] = dinv * (x[n] @ W) packed bf16x2 into 5 u32 words of an 8-word row.
__global__ void k_xw(const float* __restrict__ x, const float* __restrict__ W,
                     const int* __restrict__ pdeg, float* __restrict__ dinv,
                     unsigned* __restrict__ yw, int N) {
    __shared__ float Wt[OUT_CH][IN_CH];
    for (int i = threadIdx.x; i < IN_CH * OUT_CH; i += blockDim.x) {
        int k = i / OUT_CH, c = i - k * OUT_CH;
        Wt[c][k] = W[i];
    }
    __syncthreads();

    int n = blockIdx.x * blockDim.x + threadIdx.x;
    if (n >= N) return;

    float acc[OUT_CH];
#pragma unroll
    for (int c = 0; c < OUT_CH; ++c) acc[c] = 0.0f;

    const float4* xr = (const float4*)(x + (size_t)n * IN_CH);
#pragma unroll 4
    for (int k4 = 0; k4 < IN_CH / 4; ++k4) {
        float4 xv = xr[k4];
#pragma unroll
        for (int c = 0; c < OUT_CH; ++c) {
            float4 wv = *(const float4*)&Wt[c][k4 * 4];
            acc[c] += xv.x * wv.x + xv.y * wv.y + xv.z * wv.z + xv.w * wv.w;
        }
    }

    int b = n >> SHIFT, l = n & (NPB - 1);
    const int* pd = pdeg + ((size_t)b * DSPL) * NPB + l;
    int deg = 0;
#pragma unroll
    for (int s = 0; s < DSPL; ++s) deg += pd[(size_t)s * NPB];
    float d = rsqrtf(1.0f + (float)deg);
    dinv[n] = d;

    uint4 w0;
    w0.x = pk2(d * acc[0], d * acc[1]);
    w0.y = pk2(d * acc[2], d * acc[3]);
    w0.z = pk2(d * acc[4], d * acc[5]);
    w0.w = pk2(d * acc[6], d * acc[7]);
    *(uint4*)(yw + (size_t)n * 8) = w0;
    yw[(size_t)n * 8 + 4] = pk2(d * acc[8], d * acc[9]);
}

// 2^split_log blocks per bucket, 512 threads. Slice <= CCAP at split 16 ->
// single counting-sort round: sort by dst row in LDS (int atomics; shfl
// wave-scan prefix), each thread accumulates its 2 rows' runs of bf16
// y[src] gathers in VGPRs, partial flushed as packed bf16 (5 u32/row).
__global__ void k_accum(const int* __restrict__ pairs,
                        const int* __restrict__ bbase,
                        const int* __restrict__ gcur,
                        const unsigned* __restrict__ yw,
                        unsigned* __restrict__ part, int cap, int split_log) {
    __shared__ int hist[NPB];
    __shared__ int base[NPB];
    __shared__ int cur[NPB];
    __shared__ unsigned sorted[CCAP];
    __shared__ int wsums[8];

    int tid = threadIdx.x;
    int lane = tid & 63;
    int wid = tid >> 6;
    int b = blockIdx.x >> split_log;
    int s = blockIdx.x & ((1 << split_log) - 1);
    int beg = bbase[b];
    int c = bucket_cnt(gcur, bbase, b, cap);
    int lo = beg + (int)(((long long)c * s) >> split_log);
    int hi = beg + (int)(((long long)c * (s + 1)) >> split_log);

    int r0 = tid * 2;  // this thread owns rows r0, r0+1

    float acc[2][OUT_CH];
#pragma unroll
    for (int j = 0; j < 2; ++j)
#pragma unroll
        for (int k = 0; k < OUT_CH; ++k) acc[j][k] = 0.0f;

    for (int clo = lo; clo < hi; clo += CCAP) {
        int m = min(CCAP, hi - clo);

        hist[r0] = 0;
        hist[r0 + 1] = 0;
        __syncthreads();

        // read my <=4 pairs (static unroll), build row histogram
        unsigned mine[4];
#pragma unroll
        for (int j = 0; j < 4; ++j) {
            int i = tid + j * 512;
            if (i < m) {
                unsigned pp = (unsigned)pairs[clo + i];
                mine[j] = pp;
                atomicAdd(&hist[pp & (NPB - 1)], 1);
            }
        }
        __syncthreads();

        // exclusive scan over 1024 rows: shfl wave-scan + cross-wave fixup
        int lsum = hist[r0] + hist[r0 + 1];
        int incl = lsum;
#pragma unroll
        for (int off = 1; off < 64; off <<= 1) {
            int t = __shfl_up(incl, off);
            if (lane >= off) incl += t;
        }
        if (lane == 63) wsums[wid] = incl;
        __syncthreads();
        int run = incl - lsum;
        for (int w = 0; w < wid; ++w) run += wsums[w];
        base[r0] = run;
        cur[r0] = run;
        run += hist[r0];
        base[r0 + 1] = run;
        cur[r0 + 1] = run;
        __syncthreads();

        // scatter src ids into row-sorted LDS order
#pragma unroll
        for (int j = 0; j < 4; ++j) {
            int i = tid + j * 512;
            if (i < m) {
                unsigned pp = mine[j];
                int slot = atomicAdd(&cur[pp & (NPB - 1)], 1);
                sorted[slot] = pp >> SHIFT;
            }
        }
        __syncthreads();

        // private VGPR accumulation over my 2 rows' contiguous runs
#pragma unroll
        for (int j = 0; j < 2; ++j) {
            int rb = base[r0 + j];
            int rl = hist[r0 + j];
            for (int q = 0; q < rl; ++q) {
                unsigned src = sorted[rb + q];
                const unsigned* yr = yw + (size_t)src * 8;
                uint4 a = *(const uint4*)yr;
                unsigned w4 = yr[4];
                acc[j][0] += lo16(a.x); acc[j][1] += hi16(a.x);
                acc[j][2] += lo16(a.y); acc[j][3] += hi16(a.y);
                acc[j][4] += lo16(a.z); acc[j][5] += hi16(a.z);
                acc[j][6] += lo16(a.w); acc[j][7] += hi16(a.w);
                acc[j][8] += lo16(w4);  acc[j][9] += hi16(w4);
            }
        }
        __syncthreads();  // protect hist/sorted/wsums before next round
    }

    // flush partial as packed bf16: thread writes 40 contiguous bytes
    unsigned* dst = part + (size_t)blockIdx.x * (NPB * 5) + (size_t)r0 * 5;
#pragma unroll
    for (int j = 0; j < 2; ++j) {
        dst[j * 5 + 0] = pk2(acc[j][0], acc[j][1]);
        dst[j * 5 + 1] = pk2(acc[j][2], acc[j][3]);
        dst[j * 5 + 2] = pk2(acc[j][4], acc[j][5]);
        dst[j * 5 + 3] = pk2(acc[j][6], acc[j][7]);
        dst[j * 5 + 4] = pk2(acc[j][8], acc[j][9]);
    }
}

// Thread per (node, channel-pair): out[n][2p..2p+1] =
//   dinv[n]*(sum of split partials + y[n]) + bias. Coalesced float2 stores.
__global__ void k_merge(const unsigned* __restrict__ part,
                        const unsigned* __restrict__ yw,
                        const float* __restrict__ dinv,
                        const float* __restrict__ bias,
                        float* __restrict__ out, int N, int split_log) {
    int idx = blockIdx.x * blockDim.x + threadIdx.x;
    if (idx >= N * 5) return;
    int n = idx / 5;
    int p = idx - n * 5;
    int b = n >> SHIFT;
    int l = n & (NPB - 1);
    int spl = 1 << split_log;
    size_t slot0 = (size_t)b << split_log;
    float s0 = 0.0f, s1 = 0.0f;
    const unsigned* pp = part + slot0 * (NPB * 5) + (size_t)l * 5 + p;
    for (int q = 0; q < spl; ++q) {
        unsigned v = pp[(size_t)q * (NPB * 5)];
        s0 += lo16(v);
        s1 += hi16(v);
    }
    float d = dinv[n];
    unsigned w = yw[(size_t)n * 8 + p];
    float2 o;
    o.x = d * (s0 + lo16(w)) + bias[2 * p];
    o.y = d * (s1 + hi16(w)) + bias[2 * p + 1];
    *(float2*)(out + (size_t)n * OUT_CH + 2 * p) = o;
}

// Overflow edges' messages: out[d][:] += dinv[d] * y[s][:] (after merge).
__global__ void k_ovf_msg(const int2* __restrict__ ovf,
                          const int* __restrict__ ovfcnt,
                          const unsigned* __restrict__ yw,
                          const float* __restrict__ dinv,
                          float* __restrict__ out) {
    int cnt = *ovfcnt;
    if (cnt > OVFCAP) cnt = OVFCAP;
    int stride = gridDim.x * blockDim.x;
    for (int i = blockIdx.x * blockDim.x + threadIdx.x; i < cnt; i += stride) {
        int s = ovf[i].x;
        int d = ovf[i].y;
        float dn = dinv[d];
        const unsigned* yr = yw + (size_t)s * 8;
        uint4 a = *(const uint4*)yr;
        unsigned w4 = yr[4];
        float* orow = out + (size_t)d * OUT_CH;
        atomicAdd(&orow[0], dn * lo16(a.x));
        atomicAdd(&orow[1], dn * hi16(a.x));
        atomicAdd(&orow[2], dn * lo16(a.y));
        atomicAdd(&orow[3], dn * hi16(a.y));
        atomicAdd(&orow[4], dn * lo16(a.z));
        atomicAdd(&orow[5], dn * hi16(a.z));
        atomicAdd(&orow[6], dn * lo16(a.w));
        atomicAdd(&orow[7], dn * hi16(a.w));
        atomicAdd(&orow[8], dn * lo16(w4));
        atomicAdd(&orow[9], dn * hi16(w4));
    }
}

// ============================================================================
// Fallback path (atomic scatter) — used only if ws too small / N too large
// ============================================================================

__global__ void k_detect_fb(const unsigned int* __restrict__ w, int* flag,
                            int nwords_check) {
    __shared__ int any_nz;
    if (threadIdx.x == 0) any_nz = 0;
    __syncthreads();
    int local = 0;
    for (int i = threadIdx.x; i < nwords_check; i += blockDim.x)
        if (w[2 * i + 1] != 0u) local = 1;
    if (local) atomicOr(&any_nz, 1);
    __syncthreads();
    if (threadIdx.x == 0) *flag = any_nz;
}

__global__ void k_count_fb(const void* __restrict__ ei, int* __restrict__ cnt,
                           const int* __restrict__ flag, int E) {
    const bool is32 = (*flag != 0);
    long long i = (long long)blockIdx.x * blockDim.x + threadIdx.x;
    long long stride = (long long)gridDim.x * blockDim.x;
    for (; i < E; i += stride) atomicAdd(&cnt[load_dst(ei, is32, E, i)], 1);
}

__global__ void k_xw_fb(const float* __restrict__ x,
                        const float* __restrict__ W,
                        const int* __restrict__ cnt, float* __restrict__ dinv,
                        float* __restrict__ y, float* __restrict__ out_seed,
                        int N) {
    __shared__ float Wt[OUT_CH][IN_CH];
    for (int i = threadIdx.x; i < IN_CH * OUT_CH; i += blockDim.x) {
        int k = i / OUT_CH, c = i - k * OUT_CH;
        Wt[c][k] = W[i];
    }
    __syncthreads();
    int n = blockIdx.x * blockDim.x + threadIdx.x;
    if (n >= N) return;
    float acc[OUT_CH];
#pragma unroll
    for (int c = 0; c < OUT_CH; ++c) acc[c] = 0.0f;
    const float4* xr = (const float4*)(x + (size_t)n * IN_CH);
#pragma unroll 4
    for (int k4 = 0; k4 < IN_CH / 4; ++k4) {
        float4 xv = xr[k4];
#pragma unroll
        for (int c = 0; c < OUT_CH; ++c) {
            float4 wv = *(const float4*)&Wt[c][k4 * 4];
            acc[c] += xv.x * wv.x + xv.y * wv.y + xv.z * wv.z + xv.w * wv.w;
        }
    }
    float d = rsqrtf(1.0f + (float)cnt[n]);
    dinv[n] = d;
    float2* yr = (float2*)(y + (size_t)n * OUT_CH);
    float2* orow = (float2*)(out_seed + (size_t)n * OUT_CH);
#pragma unroll
    for (int c2 = 0; c2 < OUT_CH / 2; ++c2) {
        float2 v;
        v.x = d * acc[2 * c2];
        v.y = d * acc[2 * c2 + 1];
        yr[c2] = v;
        orow[c2] = v;
    }
}

__global__ void k_scatter_fb(const void* __restrict__ ei,
                             const float* __restrict__ y,
                             float* __restrict__ out,
                             const int* __restrict__ flag, int E) {
    const bool is32 = (*flag != 0);
    long long i = (long long)blockIdx.x * blockDim.x + threadIdx.x;
    long long stride = (long long)gridDim.x * blockDim.x;
    for (; i < E; i += stride) {
        long long s = load_src(ei, is32, E, i);
        long long t = load_dst(ei, is32, E, i);
        const float2* yr = (const float2*)(y + s * OUT_CH);
        float2 v0 = yr[0], v1 = yr[1], v2 = yr[2], v3 = yr[3], v4 = yr[4];
        float* orow = out + t * OUT_CH;
        atomicAdd(&orow[0], v0.x);
        atomicAdd(&orow[1], v0.y);
        atomicAdd(&orow[2], v1.x);
        atomicAdd(&orow[3], v1.y);
        atomicAdd(&orow[4], v2.x);
        atomicAdd(&orow[5], v2.y);
        atomicAdd(&orow[6], v3.x);
        atomicAdd(&orow[7], v3.y);
        atomicAdd(&orow[8], v4.x);
        atomicAdd(&orow[9], v4.y);
    }
}

__global__ void k_final_fb(const float* __restrict__ dinv,
                           const float* __restrict__ b,
                           float* __restrict__ out, int N) {
    int n = blockIdx.x * blockDim.x + threadIdx.x;
    if (n >= N) return;
    float d = dinv[n];
    float2* orow = (float2*)(out + (size_t)n * OUT_CH);
#pragma unroll
    for (int c2 = 0; c2 < OUT_CH / 2; ++c2) {
        float2 v = orow[c2];
        v.x = v.x * d + b[2 * c2];
        v.y = v.y * d + b[2 * c2 + 1];
        orow[c2] = v;
    }
}

// ============================================================================
// Launch
// ============================================================================

extern "C" void kernel_launch(void* const* d_in, const int* in_sizes, int n_in,
                              void* d_out, int out_size, void* d_ws,
                              size_t ws_size, hipStream_t stream) {
    const float* x = (const float*)d_in[0];
    const void* ei = d_in[1];
    const float* W = (const float*)d_in[2];
    const float* b = (const float*)d_in[3];
    float* out = (float*)d_out;

    int N = in_sizes[0] / IN_CH;  // 100000
    int E = in_sizes[1] / 2;      // 3200000

    int NB = (N + NPB - 1) >> SHIFT;  // buckets (98)
    int nblkN = (N + 255) / 256;
    int nblkC = (E + CHUNK_C - 1) / CHUNK_C;
    int nblkF = (E + CHUNK_F - 1) / CHUNK_F;

    // capacity per bucket: mean + 25% + 1024, rounded up to 16
    int cap = (E + NB - 1) / NB;
    cap += cap / 4 + 1024;
    cap = (cap + 15) & ~15;

    // common header (4B units): gcur[128]|bbase[128]|bcnt[128]|flag|ovfcnt
    size_t off_pdeg = 400;
    size_t off_dinv = off_pdeg + (size_t)NB * DSPL * NPB;
    size_t off_yw = (off_dinv + (size_t)N + 15) & ~(size_t)15;
    size_t off_pairs = off_yw + (size_t)8 * N;
    // capacity path
    size_t off_ovf = (off_pairs + (size_t)NB * cap + 15) & ~(size_t)15;
    size_t off_part_c = (off_ovf + (size_t)2 * OVFCAP + 15) & ~(size_t)15;
    // exact path
    size_t off_part_e = (off_pairs + (size_t)E + 15) & ~(size_t)15;

    // choose path + split: prefer capacity (fewer passes), split 16 then 8
    int use_cap = -1, split_log = 0;
    for (int pass = 0; pass < 2 && use_cap < 0; ++pass) {
        size_t op = pass == 0 ? off_part_c : off_part_e;
        for (int sl = 4; sl >= 3; --sl) {
            size_t needed = (op + ((size_t)NB << sl) * (NPB * 5)) * 4;
            if (ws_size >= needed) {
                use_cap = (pass == 0);
                split_log = sl;
                break;
            }
        }
    }

    bool ok_shape = (NB <= 128) && (N <= (1 << 22));

    if (ok_shape && use_cap >= 0) {
        int* wsi = (int*)d_ws;
        int* gcur = wsi;
        int* bbase = wsi + 128;
        int* bcnt = wsi + 256;
        int* flag = wsi + 384;
        int* ovfcnt = wsi + 385;
        int* pdeg = wsi + off_pdeg;
        float* dinv = (float*)(wsi + off_dinv);
        unsigned* yw = (unsigned*)(wsi + off_yw);
        int* pairs = wsi + off_pairs;
        int2* ovf = (int2*)(wsi + off_ovf);
        unsigned* part =
            (unsigned*)(wsi + (use_cap ? off_part_c : off_part_e));

        if (use_cap) {
            k_init_cap<<<1, 256, 0, stream>>>((const unsigned int*)ei, gcur,
                                              bbase, ovfcnt, flag, NB, cap,
                                              8192);
            k_binfill<<<nblkF, 512, 0, stream>>>(ei, flag, E, gcur, pairs, NB,
                                                 cap, ovf, ovfcnt);
            k_deg_part<<<NB * DSPL, 512, 0, stream>>>(pairs, bbase, gcur, pdeg,
                                                      cap);
            k_ovf_deg<<<16, 256, 0, stream>>>(ovf, ovfcnt, pdeg);
            k_xw<<<nblkN, 256, 0, stream>>>(x, W, pdeg, dinv, yw, N);
            k_accum<<<NB << split_log, 512, 0, stream>>>(pairs, bbase, gcur,
                                                         yw, part, cap,
                                                         split_log);
            int mthreads = N * 5;
            k_merge<<<(mthreads + 255) / 256, 256, 0, stream>>>(
                part, yw, dinv, b, out, N, split_log);
            k_ovf_msg<<<16, 256, 0, stream>>>(ovf, ovfcnt, yw, dinv, out);
        } else {
            k_init_exact<<<1, 256, 0, stream>>>((const unsigned int*)ei, bcnt,
                                                flag, NB, 8192);
            k_bincount<<<nblkC, 256, 0, stream>>>(ei, flag, E, bcnt, NB);
            k_scanNB<<<1, 128, 0, stream>>>(bcnt, bbase, gcur, NB);
            k_binfill<<<nblkF, 512, 0, stream>>>(ei, flag, E, gcur, pairs, NB,
                                                 0, nullptr, nullptr);
            k_deg_part<<<NB * DSPL, 512, 0, stream>>>(pairs, bbase, gcur, pdeg,
                                                      0);
            k_xw<<<nblkN, 256, 0, stream>>>(x, W, pdeg, dinv, yw, N);
            k_accum<<<NB << split_log, 512, 0, stream>>>(pairs, bbase, gcur,
                                                         yw, part, 0,
                                                         split_log);
            int mthreads = N * 5;
            k_merge<<<(mthreads + 255) / 256, 256, 0, stream>>>(
                part, yw, dinv, b, out, N, split_log);
        }
    } else {
        // -------- fallback: atomic scatter --------
        int* wsi = (int*)d_ws;
        int* cnt = wsi;                     // N
        int* flag = cnt + N;                // 1
        size_t off = ((size_t)N + 2) & ~(size_t)1;
        float* dinv = (float*)(wsi + off);  // N
        float* y = dinv + N;                // 10N

        k_zero_i<<<nblkN, 256, 0, stream>>>(cnt, N);
        k_detect_fb<<<1, 256, 0, stream>>>((const unsigned int*)ei, flag,
                                           8192);
        k_count_fb<<<4096, 256, 0, stream>>>(ei, cnt, flag, E);
        k_xw_fb<<<nblkN, 256, 0, stream>>>(x, W, cnt, dinv, y, out, N);
        k_scatter_fb<<<4096, 256, 0, stream>>>(ei, y, out, flag, E);
        k_final_fb<<<nblkN, 256, 0, stream>>>(dinv, b, out, N);
    }
}

// Round 14
// 103.454 us; speedup vs baseline: 1.5068x; 1.0739x over previous
//
#include <hip/hip_runtime.h>

#define IN_CH 128
#define OUT_CH 10
#define SHIFT 10                   // nodes per bucket = 1024
#define NPB 1024
#define CHUNK_C 2048               // bincount chunk (exact path only)
#define CHUNK_F 8192               // binfill chunk (512 thr, 16 edges/thread)
#define CCAP 2048                  // pairs per counting-sort round in k_accum
#define DSPL 8                     // deg slices per bucket
#define OVFCAP (1 << 20)           // overflow list capacity (edges)

// bf16 helpers (RNE pack, shift unpack)
__device__ __forceinline__ unsigned pk2(float a, float b) {
    unsigned ua = __float_as_uint(a);
    ua = (ua + 0x7fffu + ((ua >> 16) & 1u)) >> 16;
    unsigned ub = __float_as_uint(b);
    ub = (ub + 0x7fffu + ((ub >> 16) & 1u)) >> 16;
    return ua | (ub << 16);
}
__device__ __forceinline__ float lo16(unsigned u) {
    return __uint_as_float(u << 16);
}
__device__ __forceinline__ float hi16(unsigned u) {
    return __uint_as_float(u & 0xffff0000u);
}

__device__ __forceinline__ int load_dst(const void* ei, bool is32, long long E,
                                        long long i) {
    return is32 ? ((const int*)ei)[E + i] : (int)((const long long*)ei)[E + i];
}
__device__ __forceinline__ int load_src(const void* ei, bool is32, long long E,
                                        long long i) {
    return is32 ? ((const int*)ei)[i] : (int)((const long long*)ei)[i];
}

// ============================================================================
// Init kernels
// ============================================================================

// Capacity path: gcur[b]=bbase[b]=b*cap, ovfcnt=0, int64/int32 detect.
__global__ void k_init_cap(const unsigned int* __restrict__ w,
                           int* __restrict__ gcur, int* __restrict__ bbase,
                           int* __restrict__ ovfcnt, int* __restrict__ flag,
                           int NB, int cap, int nwords_check) {
    __shared__ int any_nz;
    int tid = threadIdx.x;
    for (int i = tid; i < NB; i += 256) {
        gcur[i] = i * cap;
        bbase[i] = i * cap;
    }
    if (tid == 0) {
        any_nz = 0;
        *ovfcnt = 0;
    }
    __syncthreads();
    int local = 0;
    for (int i = tid; i < nwords_check; i += 256)
        if (w[2 * i + 1] != 0u) local = 1;
    if (local) atomicOr(&any_nz, 1);
    __syncthreads();
    if (tid == 0) *flag = any_nz;
}

// Exact path: zero bcnt + detect.
__global__ void k_init_exact(const unsigned int* __restrict__ w,
                             int* __restrict__ bcnt, int* __restrict__ flag,
                             int NB, int nwords_check) {
    __shared__ int any_nz;
    for (int i = threadIdx.x; i < NB; i += 256) bcnt[i] = 0;
    if (threadIdx.x == 0) any_nz = 0;
    __syncthreads();
    int local = 0;
    for (int i = threadIdx.x; i < nwords_check; i += 256)
        if (w[2 * i + 1] != 0u) local = 1;
    if (local) atomicOr(&any_nz, 1);
    __syncthreads();
    if (threadIdx.x == 0) *flag = any_nz;
}

__global__ void k_zero_i(int* __restrict__ p, int n) {
    int i = blockIdx.x * blockDim.x + threadIdx.x;
    int stride = gridDim.x * blockDim.x;
    for (; i < n; i += stride) p[i] = 0;
}

// ============================================================================
// Exact-count helpers (used only when ws can't fit capacity slack)
// ============================================================================

__global__ void k_bincount(const void* __restrict__ ei,
                           const int* __restrict__ flag, int E,
                           int* __restrict__ bcnt, int NB) {
    __shared__ int h[128];
    for (int i = threadIdx.x; i < NB; i += blockDim.x) h[i] = 0;
    __syncthreads();
    const bool is32 = (*flag != 0);
    long long base = (long long)blockIdx.x * CHUNK_C;
    int lim = (int)min((long long)CHUNK_C, (long long)E - base);
    for (int i = threadIdx.x; i < lim; i += blockDim.x) {
        int d = load_dst(ei, is32, E, base + i);
        atomicAdd(&h[d >> SHIFT], 1);
    }
    __syncthreads();
    for (int i = threadIdx.x; i < NB; i += blockDim.x)
        if (h[i]) atomicAdd(&bcnt[i], h[i]);
}

// Exclusive scan -> bbase, gcur.
__global__ void k_scanNB(const int* __restrict__ bcnt, int* __restrict__ bbase,
                         int* __restrict__ gcur, int NB) {
    __shared__ int s[128];
    int tid = threadIdx.x;
    int v = (tid < NB) ? bcnt[tid] : 0;
    if (tid < 128) s[tid] = v;
    __syncthreads();
    for (int off = 1; off < 128; off <<= 1) {
        int t = (tid < 128 && tid >= off) ? s[tid - off] : 0;
        __syncthreads();
        if (tid < 128) s[tid] += t;
        __syncthreads();
    }
    if (tid < NB) {
        int e = s[tid] - v;
        bbase[tid] = e;
        gcur[tid] = e;
    }
}

// ============================================================================
// Binfill: register-cached edges (16/thread), one global-memory pass.
// cap>0: capacity-bounded segments + overflow list. cap==0: exact segments.
// ============================================================================

__global__ void k_binfill(const void* __restrict__ ei,
                          const int* __restrict__ flag, int E,
                          int* __restrict__ gcur, int* __restrict__ pairs,
                          int NB, int cap, int2* __restrict__ ovf,
                          int* __restrict__ ovfcnt) {
    __shared__ int h[128];
    __shared__ int cur[128];
    int tid = threadIdx.x;
    for (int i = tid; i < NB; i += 512) h[i] = 0;
    __syncthreads();
    const bool is32 = (*flag != 0);
    long long base = (long long)blockIdx.x * CHUNK_F;
    int lim = (int)min((long long)CHUNK_F, (long long)E - base);

    int ss[16], dd[16];
#pragma unroll
    for (int j = 0; j < 16; ++j) {
        int i = tid + j * 512;
        if (i < lim) {
            ss[j] = load_src(ei, is32, E, base + i);
            dd[j] = load_dst(ei, is32, E, base + i);
        }
    }
#pragma unroll
    for (int j = 0; j < 16; ++j) {
        int i = tid + j * 512;
        if (i < lim) atomicAdd(&h[dd[j] >> SHIFT], 1);
    }
    __syncthreads();
    for (int i = tid; i < NB; i += 512)
        cur[i] = h[i] ? atomicAdd(&gcur[i], h[i]) : 0;
    __syncthreads();
#pragma unroll
    for (int j = 0; j < 16; ++j) {
        int i = tid + j * 512;
        if (i < lim) {
            int bk = dd[j] >> SHIFT;
            int slot = atomicAdd(&cur[bk], 1);
            if (cap > 0 && slot >= (bk + 1) * cap) {
                int o = atomicAdd(ovfcnt, 1);
                if (o < OVFCAP) {
                    ovf[o].x = ss[j];
                    ovf[o].y = dd[j];
                }
            } else {
                pairs[slot] = (int)(((unsigned)ss[j] << SHIFT) |
                                    (unsigned)(dd[j] & (NPB - 1)));
            }
        }
    }
}

// bucket count from cursors: c = gcur[b]-bbase[b], clamped to cap if cap>0
__device__ __forceinline__ int bucket_cnt(const int* gcur, const int* bbase,
                                          int b, int cap) {
    int c = gcur[b] - bbase[b];
    if (cap > 0 && c > cap) c = cap;
    return c;
}

// ============================================================================
// Degree, XW, accumulate, merge
// ============================================================================

// DSPL blocks per bucket (512 threads): LDS hist of the slice's dst rows,
// flushed NON-atomically to pdeg[blockIdx][1024]. The s==0 block of each
// bucket then patches in any overflow-edge degrees for ITS OWN bucket
// (atomic, after its flush -- program order makes this safe; ovf list is
// normally empty so the scan is free).
__global__ void k_deg_part(const int* __restrict__ pairs,
                           const int* __restrict__ bbase,
                           const int* __restrict__ gcur,
                           int* __restrict__ pdeg, int cap,
                           const int2* __restrict__ ovf,
                           const int* __restrict__ ovfcnt) {
    __shared__ int hist[NPB];
    int tid = threadIdx.x;
    for (int j = tid; j < NPB; j += 512) hist[j] = 0;
    __syncthreads();
    int b = blockIdx.x >> 3;
    int s = blockIdx.x & 7;
    int beg = bbase[b];
    int c = bucket_cnt(gcur, bbase, b, cap);
    int lo = beg + (int)(((long long)c * s) >> 3);
    int hi = beg + (int)(((long long)c * (s + 1)) >> 3);
    for (int i = lo + tid; i < hi; i += 512)
        atomicAdd(&hist[((unsigned)pairs[i]) & (NPB - 1)], 1);
    __syncthreads();
    int* dst = pdeg + (size_t)blockIdx.x * NPB;
    for (int j = tid; j < NPB; j += 512) dst[j] = hist[j];

    if (ovf != nullptr && s == 0) {
        __syncthreads();  // flush visible before atomics on same region
        int cnt = *ovfcnt;
        if (cnt > OVFCAP) cnt = OVFCAP;
        for (int i = tid; i < cnt; i += 512) {
            int d = ovf[i].y;
            if ((d >> SHIFT) == b)
                atomicAdd(&dst[d & (NPB - 1)], 1);
        }
    }
}

// Per node: deg = sum of DSPL partials; dinv = rsqrt(1+deg);
// y[n] = dinv * (x[n] @ W) packed bf16x2 into 5 u32 words of an 8-word row.
__global__ void k_xw(const float* __restrict__ x, const float* __restrict__ W,
                     const int* __restrict__ pdeg, float* __restrict__ dinv,
                     unsigned* __restrict__ yw, int N) {
    __shared__ float Wt[OUT_CH][IN_CH];
    for (int i = threadIdx.x; i < IN_CH * OUT_CH; i += blockDim.x) {
        int k = i / OUT_CH, c = i - k * OUT_CH;
        Wt[c][k] = W[i];
    }
    __syncthreads();

    int n = blockIdx.x * blockDim.x + threadIdx.x;
    if (n >= N) return;

    float acc[OUT_CH];
#pragma unroll
    for (int c = 0; c < OUT_CH; ++c) acc[c] = 0.0f;

    const float4* xr = (const float4*)(x + (size_t)n * IN_CH);
#pragma unroll 4
    for (int k4 = 0; k4 < IN_CH / 4; ++k4) {
        float4 xv = xr[k4];
#pragma unroll
        for (int c = 0; c < OUT_CH; ++c) {
            float4 wv = *(const float4*)&Wt[c][k4 * 4];
            acc[c] += xv.x * wv.x + xv.y * wv.y + xv.z * wv.z + xv.w * wv.w;
        }
    }

    int b = n >> SHIFT, l = n & (NPB - 1);
    const int* pd = pdeg + ((size_t)b * DSPL) * NPB + l;
    int deg = 0;
#pragma unroll
    for (int s = 0; s < DSPL; ++s) deg += pd[(size_t)s * NPB];
    float d = rsqrtf(1.0f + (float)deg);
    dinv[n] = d;

    uint4 w0;
    w0.x = pk2(d * acc[0], d * acc[1]);
    w0.y = pk2(d * acc[2], d * acc[3]);
    w0.z = pk2(d * acc[4], d * acc[5]);
    w0.w = pk2(d * acc[6], d * acc[7]);
    *(uint4*)(yw + (size_t)n * 8) = w0;
    yw[(size_t)n * 8 + 4] = pk2(d * acc[8], d * acc[9]);
}

// 2^split_log blocks per bucket, 512 threads. Slice <= CCAP at split 16 ->
// single counting-sort round: sort by dst row in LDS (int atomics; shfl
// wave-scan prefix), each thread accumulates its 2 rows' runs of bf16
// y[src] gathers in VGPRs, partial flushed as packed bf16 (5 u32/row).
__global__ void k_accum(const int* __restrict__ pairs,
                        const int* __restrict__ bbase,
                        const int* __restrict__ gcur,
                        const unsigned* __restrict__ yw,
                        unsigned* __restrict__ part, int cap, int split_log) {
    __shared__ int hist[NPB];
    __shared__ int base[NPB];
    __shared__ int cur[NPB];
    __shared__ unsigned sorted[CCAP];
    __shared__ int wsums[8];

    int tid = threadIdx.x;
    int lane = tid & 63;
    int wid = tid >> 6;
    int b = blockIdx.x >> split_log;
    int s = blockIdx.x & ((1 << split_log) - 1);
    int beg = bbase[b];
    int c = bucket_cnt(gcur, bbase, b, cap);
    int lo = beg + (int)(((long long)c * s) >> split_log);
    int hi = beg + (int)(((long long)c * (s + 1)) >> split_log);

    int r0 = tid * 2;  // this thread owns rows r0, r0+1

    float acc[2][OUT_CH];
#pragma unroll
    for (int j = 0; j < 2; ++j)
#pragma unroll
        for (int k = 0; k < OUT_CH; ++k) acc[j][k] = 0.0f;

    for (int clo = lo; clo < hi; clo += CCAP) {
        int m = min(CCAP, hi - clo);

        hist[r0] = 0;
        hist[r0 + 1] = 0;
        __syncthreads();

        // read my <=4 pairs (static unroll), build row histogram
        unsigned mine[4];
#pragma unroll
        for (int j = 0; j < 4; ++j) {
            int i = tid + j * 512;
            if (i < m) {
                unsigned pp = (unsigned)pairs[clo + i];
                mine[j] = pp;
                atomicAdd(&hist[pp & (NPB - 1)], 1);
            }
        }
        __syncthreads();

        // exclusive scan over 1024 rows: shfl wave-scan + cross-wave fixup
        int lsum = hist[r0] + hist[r0 + 1];
        int incl = lsum;
#pragma unroll
        for (int off = 1; off < 64; off <<= 1) {
            int t = __shfl_up(incl, off);
            if (lane >= off) incl += t;
        }
        if (lane == 63) wsums[wid] = incl;
        __syncthreads();
        int run = incl - lsum;
        for (int w = 0; w < wid; ++w) run += wsums[w];
        base[r0] = run;
        cur[r0] = run;
        run += hist[r0];
        base[r0 + 1] = run;
        cur[r0 + 1] = run;
        __syncthreads();

        // scatter src ids into row-sorted LDS order
#pragma unroll
        for (int j = 0; j < 4; ++j) {
            int i = tid + j * 512;
            if (i < m) {
                unsigned pp = mine[j];
                int slot = atomicAdd(&cur[pp & (NPB - 1)], 1);
                sorted[slot] = pp >> SHIFT;
            }
        }
        __syncthreads();

        // private VGPR accumulation over my 2 rows' contiguous runs
#pragma unroll
        for (int j = 0; j < 2; ++j) {
            int rb = base[r0 + j];
            int rl = hist[r0 + j];
            for (int q = 0; q < rl; ++q) {
                unsigned src = sorted[rb + q];
                const unsigned* yr = yw + (size_t)src * 8;
                uint4 a = *(const uint4*)yr;
                unsigned w4 = yr[4];
                acc[j][0] += lo16(a.x); acc[j][1] += hi16(a.x);
                acc[j][2] += lo16(a.y); acc[j][3] += hi16(a.y);
                acc[j][4] += lo16(a.z); acc[j][5] += hi16(a.z);
                acc[j][6] += lo16(a.w); acc[j][7] += hi16(a.w);
                acc[j][8] += lo16(w4);  acc[j][9] += hi16(w4);
            }
        }
        __syncthreads();  // protect hist/sorted/wsums before next round
    }

    // flush partial as packed bf16: thread writes 40 contiguous bytes
    unsigned* dst = part + (size_t)blockIdx.x * (NPB * 5) + (size_t)r0 * 5;
#pragma unroll
    for (int j = 0; j < 2; ++j) {
        dst[j * 5 + 0] = pk2(acc[j][0], acc[j][1]);
        dst[j * 5 + 1] = pk2(acc[j][2], acc[j][3]);
        dst[j * 5 + 2] = pk2(acc[j][4], acc[j][5]);
        dst[j * 5 + 3] = pk2(acc[j][6], acc[j][7]);
        dst[j * 5 + 4] = pk2(acc[j][8], acc[j][9]);
    }
}

// Thread per (node, channel-pair): out[n][2p..2p+1] =
//   dinv[n]*(sum of split partials + y[n]) + bias. Coalesced float2 stores.
__global__ void k_merge(const unsigned* __restrict__ part,
                        const unsigned* __restrict__ yw,
                        const float* __restrict__ dinv,
                        const float* __restrict__ bias,
                        float* __restrict__ out, int N, int split_log) {
    int idx = blockIdx.x * blockDim.x + threadIdx.x;
    if (idx >= N * 5) return;
    int n = idx / 5;
    int p = idx - n * 5;
    int b = n >> SHIFT;
    int l = n & (NPB - 1);
    int spl = 1 << split_log;
    size_t slot0 = (size_t)b << split_log;
    float s0 = 0.0f, s1 = 0.0f;
    const unsigned* pp = part + slot0 * (NPB * 5) + (size_t)l * 5 + p;
    for (int q = 0; q < spl; ++q) {
        unsigned v = pp[(size_t)q * (NPB * 5)];
        s0 += lo16(v);
        s1 += hi16(v);
    }
    float d = dinv[n];
    unsigned w = yw[(size_t)n * 8 + p];
    float2 o;
    o.x = d * (s0 + lo16(w)) + bias[2 * p];
    o.y = d * (s1 + hi16(w)) + bias[2 * p + 1];
    *(float2*)(out + (size_t)n * OUT_CH + 2 * p) = o;
}

// Overflow edges' messages: out[d][:] += dinv[d] * y[s][:] (after merge).
__global__ void k_ovf_msg(const int2* __restrict__ ovf,
                          const int* __restrict__ ovfcnt,
                          const unsigned* __restrict__ yw,
                          const float* __restrict__ dinv,
                          float* __restrict__ out) {
    int cnt = *ovfcnt;
    if (cnt > OVFCAP) cnt = OVFCAP;
    int stride = gridDim.x * blockDim.x;
    for (int i = blockIdx.x * blockDim.x + threadIdx.x; i < cnt; i += stride) {
        int s = ovf[i].x;
        int d = ovf[i].y;
        float dn = dinv[d];
        const unsigned* yr = yw + (size_t)s * 8;
        uint4 a = *(const uint4*)yr;
        unsigned w4 = yr[4];
        float* orow = out + (size_t)d * OUT_CH;
        atomicAdd(&orow[0], dn * lo16(a.x));
        atomicAdd(&orow[1], dn * hi16(a.x));
        atomicAdd(&orow[2], dn * lo16(a.y));
        atomicAdd(&orow[3], dn * hi16(a.y));
        atomicAdd(&orow[4], dn * lo16(a.z));
        atomicAdd(&orow[5], dn * hi16(a.z));
        atomicAdd(&orow[6], dn * lo16(a.w));
        atomicAdd(&orow[7], dn * hi16(a.w));
        atomicAdd(&orow[8], dn * lo16(w4));
        atomicAdd(&orow[9], dn * hi16(w4));
    }
}

// ============================================================================
// Fallback path (atomic scatter) — used only if ws too small / N too large
// ============================================================================

__global__ void k_detect_fb(const unsigned int* __restrict__ w, int* flag,
                            int nwords_check) {
    __shared__ int any_nz;
    if (threadIdx.x == 0) any_nz = 0;
    __syncthreads();
    int local = 0;
    for (int i = threadIdx.x; i < nwords_check; i += blockDim.x)
        if (w[2 * i + 1] != 0u) local = 1;
    if (local) atomicOr(&any_nz, 1);
    __syncthreads();
    if (threadIdx.x == 0) *flag = any_nz;
}

__global__ void k_count_fb(const void* __restrict__ ei, int* __restrict__ cnt,
                           const int* __restrict__ flag, int E) {
    const bool is32 = (*flag != 0);
    long long i = (long long)blockIdx.x * blockDim.x + threadIdx.x;
    long long stride = (long long)gridDim.x * blockDim.x;
    for (; i < E; i += stride) atomicAdd(&cnt[load_dst(ei, is32, E, i)], 1);
}

__global__ void k_xw_fb(const float* __restrict__ x,
                        const float* __restrict__ W,
                        const int* __restrict__ cnt, float* __restrict__ dinv,
                        float* __restrict__ y, float* __restrict__ out_seed,
                        int N) {
    __shared__ float Wt[OUT_CH][IN_CH];
    for (int i = threadIdx.x; i < IN_CH * OUT_CH; i += blockDim.x) {
        int k = i / OUT_CH, c = i - k * OUT_CH;
        Wt[c][k] = W[i];
    }
    __syncthreads();
    int n = blockIdx.x * blockDim.x + threadIdx.x;
    if (n >= N) return;
    float acc[OUT_CH];
#pragma unroll
    for (int c = 0; c < OUT_CH; ++c) acc[c] = 0.0f;
    const float4* xr = (const float4*)(x + (size_t)n * IN_CH);
#pragma unroll 4
    for (int k4 = 0; k4 < IN_CH / 4; ++k4) {
        float4 xv = xr[k4];
#pragma unroll
        for (int c = 0; c < OUT_CH; ++c) {
            float4 wv = *(const float4*)&Wt[c][k4 * 4];
            acc[c] += xv.x * wv.x + xv.y * wv.y + xv.z * wv.z + xv.w * wv.w;
        }
    }
    float d = rsqrtf(1.0f + (float)cnt[n]);
    dinv[n] = d;
    float2* yr = (float2*)(y + (size_t)n * OUT_CH);
    float2* orow = (float2*)(out_seed + (size_t)n * OUT_CH);
#pragma unroll
    for (int c2 = 0; c2 < OUT_CH / 2; ++c2) {
        float2 v;
        v.x = d * acc[2 * c2];
        v.y = d * acc[2 * c2 + 1];
        yr[c2] = v;
        orow[c2] = v;
    }
}

__global__ void k_scatter_fb(const void* __restrict__ ei,
                             const float* __restrict__ y,
                             float* __restrict__ out,
                             const int* __restrict__ flag, int E) {
    const bool is32 = (*flag != 0);
    long long i = (long long)blockIdx.x * blockDim.x + threadIdx.x;
    long long stride = (long long)gridDim.x * blockDim.x;
    for (; i < E; i += stride) {
        long long s = load_src(ei, is32, E, i);
        long long t = load_dst(ei, is32, E, i);
        const float2* yr = (const float2*)(y + s * OUT_CH);
        float2 v0 = yr[0], v1 = yr[1], v2 = yr[2], v3 = yr[3], v4 = yr[4];
        float* orow = out + t * OUT_CH;
        atomicAdd(&orow[0], v0.x);
        atomicAdd(&orow[1], v0.y);
        atomicAdd(&orow[2], v1.x);
        atomicAdd(&orow[3], v1.y);
        atomicAdd(&orow[4], v2.x);
        atomicAdd(&orow[5], v2.y);
        atomicAdd(&orow[6], v3.x);
        atomicAdd(&orow[7], v3.y);
        atomicAdd(&orow[8], v4.x);
        atomicAdd(&orow[9], v4.y);
    }
}

__global__ void k_final_fb(const float* __restrict__ dinv,
                           const float* __restrict__ b,
                           float* __restrict__ out, int N) {
    int n = blockIdx.x * blockDim.x + threadIdx.x;
    if (n >= N) return;
    float d = dinv[n];
    float2* orow = (float2*)(out + (size_t)n * OUT_CH);
#pragma unroll
    for (int c2 = 0; c2 < OUT_CH / 2; ++c2) {
        float2 v = orow[c2];
        v.x = v.x * d + b[2 * c2];
        v.y = v.y * d + b[2 * c2 + 1];
        orow[c2] = v;
    }
}

// ============================================================================
// Launch
// ============================================================================

extern "C" void kernel_launch(void* const* d_in, const int* in_sizes, int n_in,
                              void* d_out, int out_size, void* d_ws,
                              size_t ws_size, hipStream_t stream) {
    const float* x = (const float*)d_in[0];
    const void* ei = d_in[1];
    const float* W = (const float*)d_in[2];
    const float* b = (const float*)d_in[3];
    float* out = (float*)d_out;

    int N = in_sizes[0] / IN_CH;  // 100000
    int E = in_sizes[1] / 2;      // 3200000

    int NB = (N + NPB - 1) >> SHIFT;  // buckets (98)
    int nblkN = (N + 255) / 256;
    int nblkC = (E + CHUNK_C - 1) / CHUNK_C;
    int nblkF = (E + CHUNK_F - 1) / CHUNK_F;

    // capacity per bucket: mean + 25% + 1024, rounded up to 16
    int cap = (E + NB - 1) / NB;
    cap += cap / 4 + 1024;
    cap = (cap + 15) & ~15;

    // common header (4B units): gcur[128]|bbase[128]|bcnt[128]|flag|ovfcnt
    size_t off_pdeg = 400;
    size_t off_dinv = off_pdeg + (size_t)NB * DSPL * NPB;
    size_t off_yw = (off_dinv + (size_t)N + 15) & ~(size_t)15;
    size_t off_pairs = off_yw + (size_t)8 * N;
    // capacity path
    size_t off_ovf = (off_pairs + (size_t)NB * cap + 15) & ~(size_t)15;
    size_t off_part_c = (off_ovf + (size_t)2 * OVFCAP + 15) & ~(size_t)15;
    // exact path
    size_t off_part_e = (off_pairs + (size_t)E + 15) & ~(size_t)15;

    // choose path + split: prefer capacity (fewer passes), split 16 then 8
    int use_cap = -1, split_log = 0;
    for (int pass = 0; pass < 2 && use_cap < 0; ++pass) {
        size_t op = pass == 0 ? off_part_c : off_part_e;
        for (int sl = 4; sl >= 3; --sl) {
            size_t needed = (op + ((size_t)NB << sl) * (NPB * 5)) * 4;
            if (ws_size >= needed) {
                use_cap = (pass == 0);
                split_log = sl;
                break;
            }
        }
    }

    bool ok_shape = (NB <= 128) && (N <= (1 << 22));

    if (ok_shape && use_cap >= 0) {
        int* wsi = (int*)d_ws;
        int* gcur = wsi;
        int* bbase = wsi + 128;
        int* bcnt = wsi + 256;
        int* flag = wsi + 384;
        int* ovfcnt = wsi + 385;
        int* pdeg = wsi + off_pdeg;
        float* dinv = (float*)(wsi + off_dinv);
        unsigned* yw = (unsigned*)(wsi + off_yw);
        int* pairs = wsi + off_pairs;
        int2* ovf = (int2*)(wsi + off_ovf);
        unsigned* part =
            (unsigned*)(wsi + (use_cap ? off_part_c : off_part_e));

        if (use_cap) {
            k_init_cap<<<1, 256, 0, stream>>>((const unsigned int*)ei, gcur,
                                              bbase, ovfcnt, flag, NB, cap,
                                              8192);
            k_binfill<<<nblkF, 512, 0, stream>>>(ei, flag, E, gcur, pairs, NB,
                                                 cap, ovf, ovfcnt);
            k_deg_part<<<NB * DSPL, 512, 0, stream>>>(pairs, bbase, gcur, pdeg,
                                                      cap, ovf, ovfcnt);
            k_xw<<<nblkN, 256, 0, stream>>>(x, W, pdeg, dinv, yw, N);
            k_accum<<<NB << split_log, 512, 0, stream>>>(pairs, bbase, gcur,
                                                         yw, part, cap,
                                                         split_log);
            int mthreads = N * 5;
            k_merge<<<(mthreads + 255) / 256, 256, 0, stream>>>(
                part, yw, dinv, b, out, N, split_log);
            k_ovf_msg<<<16, 256, 0, stream>>>(ovf, ovfcnt, yw, dinv, out);
        } else {
            k_init_exact<<<1, 256, 0, stream>>>((const unsigned int*)ei, bcnt,
                                                flag, NB, 8192);
            k_bincount<<<nblkC, 256, 0, stream>>>(ei, flag, E, bcnt, NB);
            k_scanNB<<<1, 128, 0, stream>>>(bcnt, bbase, gcur, NB);
            k_binfill<<<nblkF, 512, 0, stream>>>(ei, flag, E, gcur, pairs, NB,
                                                 0, nullptr, nullptr);
            k_deg_part<<<NB * DSPL, 512, 0, stream>>>(pairs, bbase, gcur, pdeg,
                                                      0, nullptr, nullptr);
            k_xw<<<nblkN, 256, 0, stream>>>(x, W, pdeg, dinv, yw, N);
            k_accum<<<NB << split_log, 512, 0, stream>>>(pairs, bbase, gcur,
                                                         yw, part, 0,
                                                         split_log);
            int mthreads = N * 5;
            k_merge<<<(mthreads + 255) / 256, 256, 0, stream>>>(
                part, yw, dinv, b, out, N, split_log);
        }
    } else {
        // -------- fallback: atomic scatter --------
        int* wsi = (int*)d_ws;
        int* cnt = wsi;                     // N
        int* flag = cnt + N;                // 1
        size_t off = ((size_t)N + 2) & ~(size_t)1;
        float* dinv = (float*)(wsi + off);  // N
        float* y = dinv + N;                // 10N

        k_zero_i<<<nblkN, 256, 0, stream>>>(cnt, N);
        k_detect_fb<<<1, 256, 0, stream>>>((const unsigned int*)ei, flag,
                                           8192);
        k_count_fb<<<4096, 256, 0, stream>>>(ei, cnt, flag, E);
        k_xw_fb<<<nblkN, 256, 0, stream>>>(x, W, cnt, dinv, y, out, N);
        k_scatter_fb<<<4096, 256, 0, stream>>>(ei, y, out, flag, E);
        k_final_fb<<<nblkN, 256, 0, stream>>>(dinv, b, out, N);
    }
}

// Round 15
// 103.014 us; speedup vs baseline: 1.5132x; 1.0043x over previous
//
#include <hip/hip_runtime.h>

#define IN_CH 128
#define OUT_CH 10
#define SHIFT 10                   // nodes per bucket = 1024
#define NPB 1024
#define CHUNK_C 2048               // bincount chunk (exact path only)
#define CHUNK_F 8192               // binfill chunk (512 thr, 16 edges/thread)
#define CCAP 2048                  // pairs per counting-sort round in k_accum
#define DSPL 8                     // deg slices per bucket
#define OVFCAP (1 << 20)           // overflow list capacity (edges)

// bf16 helpers (RNE pack, shift unpack)
__device__ __forceinline__ unsigned pk2(float a, float b) {
    unsigned ua = __float_as_uint(a);
    ua = (ua + 0x7fffu + ((ua >> 16) & 1u)) >> 16;
    unsigned ub = __float_as_uint(b);
    ub = (ub + 0x7fffu + ((ub >> 16) & 1u)) >> 16;
    return ua | (ub << 16);
}
__device__ __forceinline__ float lo16(unsigned u) {
    return __uint_as_float(u << 16);
}
__device__ __forceinline__ float hi16(unsigned u) {
    return __uint_as_float(u & 0xffff0000u);
}

__device__ __forceinline__ int load_dst(const void* ei, bool is32, long long E,
                                        long long i) {
    return is32 ? ((const int*)ei)[E + i] : (int)((const long long*)ei)[E + i];
}
__device__ __forceinline__ int load_src(const void* ei, bool is32, long long E,
                                        long long i) {
    return is32 ? ((const int*)ei)[i] : (int)((const long long*)ei)[i];
}

// ============================================================================
// Init kernels
// ============================================================================

// Capacity path: gcur[b]=bbase[b]=b*cap, ovfcnt=0, int64/int32 detect.
__global__ void k_init_cap(const unsigned int* __restrict__ w,
                           int* __restrict__ gcur, int* __restrict__ bbase,
                           int* __restrict__ ovfcnt, int* __restrict__ flag,
                           int NB, int cap, int nwords_check) {
    __shared__ int any_nz;
    int tid = threadIdx.x;
    for (int i = tid; i < NB; i += 256) {
        gcur[i] = i * cap;
        bbase[i] = i * cap;
    }
    if (tid == 0) {
        any_nz = 0;
        *ovfcnt = 0;
    }
    __syncthreads();
    int local = 0;
    for (int i = tid; i < nwords_check; i += 256)
        if (w[2 * i + 1] != 0u) local = 1;
    if (local) atomicOr(&any_nz, 1);
    __syncthreads();
    if (tid == 0) *flag = any_nz;
}

// Exact path: zero bcnt + detect.
__global__ void k_init_exact(const unsigned int* __restrict__ w,
                             int* __restrict__ bcnt, int* __restrict__ flag,
                             int NB, int nwords_check) {
    __shared__ int any_nz;
    for (int i = threadIdx.x; i < NB; i += 256) bcnt[i] = 0;
    if (threadIdx.x == 0) any_nz = 0;
    __syncthreads();
    int local = 0;
    for (int i = threadIdx.x; i < nwords_check; i += 256)
        if (w[2 * i + 1] != 0u) local = 1;
    if (local) atomicOr(&any_nz, 1);
    __syncthreads();
    if (threadIdx.x == 0) *flag = any_nz;
}

__global__ void k_zero_i(int* __restrict__ p, int n) {
    int i = blockIdx.x * blockDim.x + threadIdx.x;
    int stride = gridDim.x * blockDim.x;
    for (; i < n; i += stride) p[i] = 0;
}

// ============================================================================
// Exact-count helpers (used only when ws can't fit capacity slack)
// ============================================================================

__global__ void k_bincount(const void* __restrict__ ei,
                           const int* __restrict__ flag, int E,
                           int* __restrict__ bcnt, int NB) {
    __shared__ int h[128];
    for (int i = threadIdx.x; i < NB; i += blockDim.x) h[i] = 0;
    __syncthreads();
    const bool is32 = (*flag != 0);
    long long base = (long long)blockIdx.x * CHUNK_C;
    int lim = (int)min((long long)CHUNK_C, (long long)E - base);
    for (int i = threadIdx.x; i < lim; i += blockDim.x) {
        int d = load_dst(ei, is32, E, base + i);
        atomicAdd(&h[d >> SHIFT], 1);
    }
    __syncthreads();
    for (int i = threadIdx.x; i < NB; i += blockDim.x)
        if (h[i]) atomicAdd(&bcnt[i], h[i]);
}

// Exclusive scan -> bbase, gcur.
__global__ void k_scanNB(const int* __restrict__ bcnt, int* __restrict__ bbase,
                         int* __restrict__ gcur, int NB) {
    __shared__ int s[128];
    int tid = threadIdx.x;
    int v = (tid < NB) ? bcnt[tid] : 0;
    if (tid < 128) s[tid] = v;
    __syncthreads();
    for (int off = 1; off < 128; off <<= 1) {
        int t = (tid < 128 && tid >= off) ? s[tid - off] : 0;
        __syncthreads();
        if (tid < 128) s[tid] += t;
        __syncthreads();
    }
    if (tid < NB) {
        int e = s[tid] - v;
        bbase[tid] = e;
        gcur[tid] = e;
    }
}

// ============================================================================
// Binfill: register-cached edges (16/thread), one global-memory pass.
// Rank-from-histogram: the first atomicAdd's return value is this edge's
// rank within its bucket for this block, so the write phase needs NO second
// atomic -- slot = global_run_base[bk] + rank.
// cap>0: capacity-bounded segments + overflow list. cap==0: exact segments.
// ============================================================================

__global__ void k_binfill(const void* __restrict__ ei,
                          const int* __restrict__ flag, int E,
                          int* __restrict__ gcur, int* __restrict__ pairs,
                          int NB, int cap, int2* __restrict__ ovf,
                          int* __restrict__ ovfcnt) {
    __shared__ int h[128];
    __shared__ int gbase[128];
    int tid = threadIdx.x;
    for (int i = tid; i < NB; i += 512) h[i] = 0;
    __syncthreads();
    const bool is32 = (*flag != 0);
    long long base = (long long)blockIdx.x * CHUNK_F;
    int lim = (int)min((long long)CHUNK_F, (long long)E - base);

    int ss[16], dd[16];
    int rank[16];
#pragma unroll
    for (int j = 0; j < 16; ++j) {
        int i = tid + j * 512;
        if (i < lim) {
            ss[j] = load_src(ei, is32, E, base + i);
            dd[j] = load_dst(ei, is32, E, base + i);
        }
    }
#pragma unroll
    for (int j = 0; j < 16; ++j) {
        int i = tid + j * 512;
        if (i < lim) rank[j] = atomicAdd(&h[dd[j] >> SHIFT], 1);
    }
    __syncthreads();
    for (int i = tid; i < NB; i += 512)
        gbase[i] = h[i] ? atomicAdd(&gcur[i], h[i]) : 0;
    __syncthreads();
#pragma unroll
    for (int j = 0; j < 16; ++j) {
        int i = tid + j * 512;
        if (i < lim) {
            int bk = dd[j] >> SHIFT;
            int slot = gbase[bk] + rank[j];
            if (cap > 0 && slot >= (bk + 1) * cap) {
                int o = atomicAdd(ovfcnt, 1);
                if (o < OVFCAP) {
                    ovf[o].x = ss[j];
                    ovf[o].y = dd[j];
                }
            } else {
                pairs[slot] = (int)(((unsigned)ss[j] << SHIFT) |
                                    (unsigned)(dd[j] & (NPB - 1)));
            }
        }
    }
}

// bucket count from cursors: c = gcur[b]-bbase[b], clamped to cap if cap>0
__device__ __forceinline__ int bucket_cnt(const int* gcur, const int* bbase,
                                          int b, int cap) {
    int c = gcur[b] - bbase[b];
    if (cap > 0 && c > cap) c = cap;
    return c;
}

// ============================================================================
// Degree, XW, accumulate, merge
// ============================================================================

// DSPL blocks per bucket (512 threads): LDS hist of the slice's dst rows,
// flushed NON-atomically to pdeg[blockIdx][1024]. The s==0 block of each
// bucket then patches in any overflow-edge degrees for ITS OWN bucket.
__global__ void k_deg_part(const int* __restrict__ pairs,
                           const int* __restrict__ bbase,
                           const int* __restrict__ gcur,
                           int* __restrict__ pdeg, int cap,
                           const int2* __restrict__ ovf,
                           const int* __restrict__ ovfcnt) {
    __shared__ int hist[NPB];
    int tid = threadIdx.x;
    for (int j = tid; j < NPB; j += 512) hist[j] = 0;
    __syncthreads();
    int b = blockIdx.x >> 3;
    int s = blockIdx.x & 7;
    int beg = bbase[b];
    int c = bucket_cnt(gcur, bbase, b, cap);
    int lo = beg + (int)(((long long)c * s) >> 3);
    int hi = beg + (int)(((long long)c * (s + 1)) >> 3);
    for (int i = lo + tid; i < hi; i += 512)
        atomicAdd(&hist[((unsigned)pairs[i]) & (NPB - 1)], 1);
    __syncthreads();
    int* dst = pdeg + (size_t)blockIdx.x * NPB;
    for (int j = tid; j < NPB; j += 512) dst[j] = hist[j];

    if (ovf != nullptr && s == 0) {
        __syncthreads();  // flush visible before atomics on same region
        int cnt = *ovfcnt;
        if (cnt > OVFCAP) cnt = OVFCAP;
        for (int i = tid; i < cnt; i += 512) {
            int d = ovf[i].y;
            if ((d >> SHIFT) == b)
                atomicAdd(&dst[d & (NPB - 1)], 1);
        }
    }
}

// Per node: deg = sum of DSPL partials; dinv = rsqrt(1+deg);
// y[n] = dinv * (x[n] @ W) packed bf16x2 into 5 u32 words of an 8-word row.
__global__ void k_xw(const float* __restrict__ x, const float* __restrict__ W,
                     const int* __restrict__ pdeg, float* __restrict__ dinv,
                     unsigned* __restrict__ yw, int N) {
    __shared__ float Wt[OUT_CH][IN_CH];
    for (int i = threadIdx.x; i < IN_CH * OUT_CH; i += blockDim.x) {
        int k = i / OUT_CH, c = i - k * OUT_CH;
        Wt[c][k] = W[i];
    }
    __syncthreads();

    int n = blockIdx.x * blockDim.x + threadIdx.x;
    if (n >= N) return;

    float acc[OUT_CH];
#pragma unroll
    for (int c = 0; c < OUT_CH; ++c) acc[c] = 0.0f;

    const float4* xr = (const float4*)(x + (size_t)n * IN_CH);
#pragma unroll 4
    for (int k4 = 0; k4 < IN_CH / 4; ++k4) {
        float4 xv = xr[k4];
#pragma unroll
        for (int c = 0; c < OUT_CH; ++c) {
            float4 wv = *(const float4*)&Wt[c][k4 * 4];
            acc[c] += xv.x * wv.x + xv.y * wv.y + xv.z * wv.z + xv.w * wv.w;
        }
    }

    int b = n >> SHIFT, l = n & (NPB - 1);
    const int* pd = pdeg + ((size_t)b * DSPL) * NPB + l;
    int deg = 0;
#pragma unroll
    for (int s = 0; s < DSPL; ++s) deg += pd[(size_t)s * NPB];
    float d = rsqrtf(1.0f + (float)deg);
    dinv[n] = d;

    uint4 w0;
    w0.x = pk2(d * acc[0], d * acc[1]);
    w0.y = pk2(d * acc[2], d * acc[3]);
    w0.z = pk2(d * acc[4], d * acc[5]);
    w0.w = pk2(d * acc[6], d * acc[7]);
    *(uint4*)(yw + (size_t)n * 8) = w0;
    yw[(size_t)n * 8 + 4] = pk2(d * acc[8], d * acc[9]);
}

// 2^split_log blocks per bucket, 512 threads. Single counting-sort round at
// split 16 (slice <= CCAP). Rank-from-histogram: hist atomicAdd returns the
// in-row rank, so the scatter is plain LDS stores (slot = base[row]+rank) --
// no cursor array, no second atomic pass. Each thread then accumulates its
// 2 rows' contiguous runs of bf16 y[src] gathers in VGPRs; partial flushed
// as packed bf16 (5 u32/row). No float atomics anywhere.
__global__ void k_accum(const int* __restrict__ pairs,
                        const int* __restrict__ bbase,
                        const int* __restrict__ gcur,
                        const unsigned* __restrict__ yw,
                        unsigned* __restrict__ part, int cap, int split_log) {
    __shared__ int hist[NPB];
    __shared__ int base[NPB];
    __shared__ unsigned sorted[CCAP];
    __shared__ int wsums[8];

    int tid = threadIdx.x;
    int lane = tid & 63;
    int wid = tid >> 6;
    int b = blockIdx.x >> split_log;
    int s = blockIdx.x & ((1 << split_log) - 1);
    int beg = bbase[b];
    int c = bucket_cnt(gcur, bbase, b, cap);
    int lo = beg + (int)(((long long)c * s) >> split_log);
    int hi = beg + (int)(((long long)c * (s + 1)) >> split_log);

    int r0 = tid * 2;  // this thread owns rows r0, r0+1

    float acc[2][OUT_CH];
#pragma unroll
    for (int j = 0; j < 2; ++j)
#pragma unroll
        for (int k = 0; k < OUT_CH; ++k) acc[j][k] = 0.0f;

    for (int clo = lo; clo < hi; clo += CCAP) {
        int m = min(CCAP, hi - clo);

        hist[r0] = 0;
        hist[r0 + 1] = 0;
        __syncthreads();

        // read my <=4 pairs; hist atomicAdd returns in-row rank
        unsigned mine[4];
        int rank[4];
#pragma unroll
        for (int j = 0; j < 4; ++j) {
            int i = tid + j * 512;
            if (i < m) {
                unsigned pp = (unsigned)pairs[clo + i];
                mine[j] = pp;
                rank[j] = atomicAdd(&hist[pp & (NPB - 1)], 1);
            }
        }
        __syncthreads();

        // exclusive scan over 1024 rows: shfl wave-scan + cross-wave fixup
        int lsum = hist[r0] + hist[r0 + 1];
        int incl = lsum;
#pragma unroll
        for (int off = 1; off < 64; off <<= 1) {
            int t = __shfl_up(incl, off);
            if (lane >= off) incl += t;
        }
        if (lane == 63) wsums[wid] = incl;
        __syncthreads();
        int run = incl - lsum;
        for (int w = 0; w < wid; ++w) run += wsums[w];
        base[r0] = run;
        base[r0 + 1] = run + hist[r0];
        __syncthreads();

        // scatter src ids into row-sorted LDS order (plain stores)
#pragma unroll
        for (int j = 0; j < 4; ++j) {
            int i = tid + j * 512;
            if (i < m)
                sorted[base[mine[j] & (NPB - 1)] + rank[j]] = mine[j] >> SHIFT;
        }
        __syncthreads();

        // private VGPR accumulation over my 2 rows' contiguous runs
#pragma unroll
        for (int j = 0; j < 2; ++j) {
            int rb = base[r0 + j];
            int rl = hist[r0 + j];
            for (int q = 0; q < rl; ++q) {
                unsigned src = sorted[rb + q];
                const unsigned* yr = yw + (size_t)src * 8;
                uint4 a = *(const uint4*)yr;
                unsigned w4 = yr[4];
                acc[j][0] += lo16(a.x); acc[j][1] += hi16(a.x);
                acc[j][2] += lo16(a.y); acc[j][3] += hi16(a.y);
                acc[j][4] += lo16(a.z); acc[j][5] += hi16(a.z);
                acc[j][6] += lo16(a.w); acc[j][7] += hi16(a.w);
                acc[j][8] += lo16(w4);  acc[j][9] += hi16(w4);
            }
        }
        __syncthreads();  // protect hist/sorted/wsums before next round
    }

    // flush partial as packed bf16: thread writes 40 contiguous bytes
    unsigned* dst = part + (size_t)blockIdx.x * (NPB * 5) + (size_t)r0 * 5;
#pragma unroll
    for (int j = 0; j < 2; ++j) {
        dst[j * 5 + 0] = pk2(acc[j][0], acc[j][1]);
        dst[j * 5 + 1] = pk2(acc[j][2], acc[j][3]);
        dst[j * 5 + 2] = pk2(acc[j][4], acc[j][5]);
        dst[j * 5 + 3] = pk2(acc[j][6], acc[j][7]);
        dst[j * 5 + 4] = pk2(acc[j][8], acc[j][9]);
    }
}

// Thread per (node, channel-pair): out[n][2p..2p+1] =
//   dinv[n]*(sum of split partials + y[n]) + bias. Coalesced float2 stores.
__global__ void k_merge(const unsigned* __restrict__ part,
                        const unsigned* __restrict__ yw,
                        const float* __restrict__ dinv,
                        const float* __restrict__ bias,
                        float* __restrict__ out, int N, int split_log) {
    int idx = blockIdx.x * blockDim.x + threadIdx.x;
    if (idx >= N * 5) return;
    int n = idx / 5;
    int p = idx - n * 5;
    int b = n >> SHIFT;
    int l = n & (NPB - 1);
    int spl = 1 << split_log;
    size_t slot0 = (size_t)b << split_log;
    float s0 = 0.0f, s1 = 0.0f;
    const unsigned* pp = part + slot0 * (NPB * 5) + (size_t)l * 5 + p;
    for (int q = 0; q < spl; ++q) {
        unsigned v = pp[(size_t)q * (NPB * 5)];
        s0 += lo16(v);
        s1 += hi16(v);
    }
    float d = dinv[n];
    unsigned w = yw[(size_t)n * 8 + p];
    float2 o;
    o.x = d * (s0 + lo16(w)) + bias[2 * p];
    o.y = d * (s1 + hi16(w)) + bias[2 * p + 1];
    *(float2*)(out + (size_t)n * OUT_CH + 2 * p) = o;
}

// Overflow edges' messages: out[d][:] += dinv[d] * y[s][:] (after merge).
__global__ void k_ovf_msg(const int2* __restrict__ ovf,
                          const int* __restrict__ ovfcnt,
                          const unsigned* __restrict__ yw,
                          const float* __restrict__ dinv,
                          float* __restrict__ out) {
    int cnt = *ovfcnt;
    if (cnt > OVFCAP) cnt = OVFCAP;
    int stride = gridDim.x * blockDim.x;
    for (int i = blockIdx.x * blockDim.x + threadIdx.x; i < cnt; i += stride) {
        int s = ovf[i].x;
        int d = ovf[i].y;
        float dn = dinv[d];
        const unsigned* yr = yw + (size_t)s * 8;
        uint4 a = *(const uint4*)yr;
        unsigned w4 = yr[4];
        float* orow = out + (size_t)d * OUT_CH;
        atomicAdd(&orow[0], dn * lo16(a.x));
        atomicAdd(&orow[1], dn * hi16(a.x));
        atomicAdd(&orow[2], dn * lo16(a.y));
        atomicAdd(&orow[3], dn * hi16(a.y));
        atomicAdd(&orow[4], dn * lo16(a.z));
        atomicAdd(&orow[5], dn * hi16(a.z));
        atomicAdd(&orow[6], dn * lo16(a.w));
        atomicAdd(&orow[7], dn * hi16(a.w));
        atomicAdd(&orow[8], dn * lo16(w4));
        atomicAdd(&orow[9], dn * hi16(w4));
    }
}

// ============================================================================
// Fallback path (atomic scatter) — used only if ws too small / N too large
// ============================================================================

__global__ void k_detect_fb(const unsigned int* __restrict__ w, int* flag,
                            int nwords_check) {
    __shared__ int any_nz;
    if (threadIdx.x == 0) any_nz = 0;
    __syncthreads();
    int local = 0;
    for (int i = threadIdx.x; i < nwords_check; i += blockDim.x)
        if (w[2 * i + 1] != 0u) local = 1;
    if (local) atomicOr(&any_nz, 1);
    __syncthreads();
    if (threadIdx.x == 0) *flag = any_nz;
}

__global__ void k_count_fb(const void* __restrict__ ei, int* __restrict__ cnt,
                           const int* __restrict__ flag, int E) {
    const bool is32 = (*flag != 0);
    long long i = (long long)blockIdx.x * blockDim.x + threadIdx.x;
    long long stride = (long long)gridDim.x * blockDim.x;
    for (; i < E; i += stride) atomicAdd(&cnt[load_dst(ei, is32, E, i)], 1);
}

__global__ void k_xw_fb(const float* __restrict__ x,
                        const float* __restrict__ W,
                        const int* __restrict__ cnt, float* __restrict__ dinv,
                        float* __restrict__ y, float* __restrict__ out_seed,
                        int N) {
    __shared__ float Wt[OUT_CH][IN_CH];
    for (int i = threadIdx.x; i < IN_CH * OUT_CH; i += blockDim.x) {
        int k = i / OUT_CH, c = i - k * OUT_CH;
        Wt[c][k] = W[i];
    }
    __syncthreads();
    int n = blockIdx.x * blockDim.x + threadIdx.x;
    if (n >= N) return;
    float acc[OUT_CH];
#pragma unroll
    for (int c = 0; c < OUT_CH; ++c) acc[c] = 0.0f;
    const float4* xr = (const float4*)(x + (size_t)n * IN_CH);
#pragma unroll 4
    for (int k4 = 0; k4 < IN_CH / 4; ++k4) {
        float4 xv = xr[k4];
#pragma unroll
        for (int c = 0; c < OUT_CH; ++c) {
            float4 wv = *(const float4*)&Wt[c][k4 * 4];
            acc[c] += xv.x * wv.x + xv.y * wv.y + xv.z * wv.z + xv.w * wv.w;
        }
    }
    float d = rsqrtf(1.0f + (float)cnt[n]);
    dinv[n] = d;
    float2* yr = (float2*)(y + (size_t)n * OUT_CH);
    float2* orow = (float2*)(out_seed + (size_t)n * OUT_CH);
#pragma unroll
    for (int c2 = 0; c2 < OUT_CH / 2; ++c2) {
        float2 v;
        v.x = d * acc[2 * c2];
        v.y = d * acc[2 * c2 + 1];
        yr[c2] = v;
        orow[c2] = v;
    }
}

__global__ void k_scatter_fb(const void* __restrict__ ei,
                             const float* __restrict__ y,
                             float* __restrict__ out,
                             const int* __restrict__ flag, int E) {
    const bool is32 = (*flag != 0);
    long long i = (long long)blockIdx.x * blockDim.x + threadIdx.x;
    long long stride = (long long)gridDim.x * blockDim.x;
    for (; i < E; i += stride) {
        long long s = load_src(ei, is32, E, i);
        long long t = load_dst(ei, is32, E, i);
        const float2* yr = (const float2*)(y + s * OUT_CH);
        float2 v0 = yr[0], v1 = yr[1], v2 = yr[2], v3 = yr[3], v4 = yr[4];
        float* orow = out + t * OUT_CH;
        atomicAdd(&orow[0], v0.x);
        atomicAdd(&orow[1], v0.y);
        atomicAdd(&orow[2], v1.x);
        atomicAdd(&orow[3], v1.y);
        atomicAdd(&orow[4], v2.x);
        atomicAdd(&orow[5], v2.y);
        atomicAdd(&orow[6], v3.x);
        atomicAdd(&orow[7], v3.y);
        atomicAdd(&orow[8], v4.x);
        atomicAdd(&orow[9], v4.y);
    }
}

__global__ void k_final_fb(const float* __restrict__ dinv,
                           const float* __restrict__ b,
                           float* __restrict__ out, int N) {
    int n = blockIdx.x * blockDim.x + threadIdx.x;
    if (n >= N) return;
    float d = dinv[n];
    float2* orow = (float2*)(out + (size_t)n * OUT_CH);
#pragma unroll
    for (int c2 = 0; c2 < OUT_CH / 2; ++c2) {
        float2 v = orow[c2];
        v.x = v.x * d + b[2 * c2];
        v.y = v.y * d + b[2 * c2 + 1];
        orow[c2] = v;
    }
}

// ============================================================================
// Launch
// ============================================================================

extern "C" void kernel_launch(void* const* d_in, const int* in_sizes, int n_in,
                              void* d_out, int out_size, void* d_ws,
                              size_t ws_size, hipStream_t stream) {
    const float* x = (const float*)d_in[0];
    const void* ei = d_in[1];
    const float* W = (const float*)d_in[2];
    const float* b = (const float*)d_in[3];
    float* out = (float*)d_out;

    int N = in_sizes[0] / IN_CH;  // 100000
    int E = in_sizes[1] / 2;      // 3200000

    int NB = (N + NPB - 1) >> SHIFT;  // buckets (98)
    int nblkN = (N + 255) / 256;
    int nblkC = (E + CHUNK_C - 1) / CHUNK_C;
    int nblkF = (E + CHUNK_F - 1) / CHUNK_F;

    // capacity per bucket: mean + 25% + 1024, rounded up to 16
    int cap = (E + NB - 1) / NB;
    cap += cap / 4 + 1024;
    cap = (cap + 15) & ~15;

    // common header (4B units): gcur[128]|bbase[128]|bcnt[128]|flag|ovfcnt
    size_t off_pdeg = 400;
    size_t off_dinv = off_pdeg + (size_t)NB * DSPL * NPB;
    size_t off_yw = (off_dinv + (size_t)N + 15) & ~(size_t)15;
    size_t off_pairs = off_yw + (size_t)8 * N;
    // capacity path
    size_t off_ovf = (off_pairs + (size_t)NB * cap + 15) & ~(size_t)15;
    size_t off_part_c = (off_ovf + (size_t)2 * OVFCAP + 15) & ~(size_t)15;
    // exact path
    size_t off_part_e = (off_pairs + (size_t)E + 15) & ~(size_t)15;

    // choose path + split: prefer capacity (fewer passes), split 16 then 8
    int use_cap = -1, split_log = 0;
    for (int pass = 0; pass < 2 && use_cap < 0; ++pass) {
        size_t op = pass == 0 ? off_part_c : off_part_e;
        for (int sl = 4; sl >= 3; --sl) {
            size_t needed = (op + ((size_t)NB << sl) * (NPB * 5)) * 4;
            if (ws_size >= needed) {
                use_cap = (pass == 0);
                split_log = sl;
                break;
            }
        }
    }

    bool ok_shape = (NB <= 128) && (N <= (1 << 22));

    if (ok_shape && use_cap >= 0) {
        int* wsi = (int*)d_ws;
        int* gcur = wsi;
        int* bbase = wsi + 128;
        int* bcnt = wsi + 256;
        int* flag = wsi + 384;
        int* ovfcnt = wsi + 385;
        int* pdeg = wsi + off_pdeg;
        float* dinv = (float*)(wsi + off_dinv);
        unsigned* yw = (unsigned*)(wsi + off_yw);
        int* pairs = wsi + off_pairs;
        int2* ovf = (int2*)(wsi + off_ovf);
        unsigned* part =
            (unsigned*)(wsi + (use_cap ? off_part_c : off_part_e));

        if (use_cap) {
            k_init_cap<<<1, 256, 0, stream>>>((const unsigned int*)ei, gcur,
                                              bbase, ovfcnt, flag, NB, cap,
                                              8192);
            k_binfill<<<nblkF, 512, 0, stream>>>(ei, flag, E, gcur, pairs, NB,
                                                 cap, ovf, ovfcnt);
            k_deg_part<<<NB * DSPL, 512, 0, stream>>>(pairs, bbase, gcur, pdeg,
                                                      cap, ovf, ovfcnt);
            k_xw<<<nblkN, 256, 0, stream>>>(x, W, pdeg, dinv, yw, N);
            k_accum<<<NB << split_log, 512, 0, stream>>>(pairs, bbase, gcur,
                                                         yw, part, cap,
                                                         split_log);
            int mthreads = N * 5;
            k_merge<<<(mthreads + 255) / 256, 256, 0, stream>>>(
                part, yw, dinv, b, out, N, split_log);
            k_ovf_msg<<<16, 256, 0, stream>>>(ovf, ovfcnt, yw, dinv, out);
        } else {
            k_init_exact<<<1, 256, 0, stream>>>((const unsigned int*)ei, bcnt,
                                                flag, NB, 8192);
            k_bincount<<<nblkC, 256, 0, stream>>>(ei, flag, E, bcnt, NB);
            k_scanNB<<<1, 128, 0, stream>>>(bcnt, bbase, gcur, NB);
            k_binfill<<<nblkF, 512, 0, stream>>>(ei, flag, E, gcur, pairs, NB,
                                                 0, nullptr, nullptr);
            k_deg_part<<<NB * DSPL, 512, 0, stream>>>(pairs, bbase, gcur, pdeg,
                                                      0, nullptr, nullptr);
            k_xw<<<nblkN, 256, 0, stream>>>(x, W, pdeg, dinv, yw, N);
            k_accum<<<NB << split_log, 512, 0, stream>>>(pairs, bbase, gcur,
                                                         yw, part, 0,
                                                         split_log);
            int mthreads = N * 5;
            k_merge<<<(mthreads + 255) / 256, 256, 0, stream>>>(
                part, yw, dinv, b, out, N, split_log);
        }
    } else {
        // -------- fallback: atomic scatter --------
        int* wsi = (int*)d_ws;
        int* cnt = wsi;                     // N
        int* flag = cnt + N;                // 1
        size_t off = ((size_t)N + 2) & ~(size_t)1;
        float* dinv = (float*)(wsi + off);  // N
        float* y = dinv + N;                // 10N

        k_zero_i<<<nblkN, 256, 0, stream>>>(cnt, N);
        k_detect_fb<<<1, 256, 0, stream>>>((const unsigned int*)ei, flag,
                                           8192);
        k_count_fb<<<4096, 256, 0, stream>>>(ei, cnt, flag, E);
        k_xw_fb<<<nblkN, 256, 0, stream>>>(x, W, cnt, dinv, y, out, N);
        k_scatter_fb<<<4096, 256, 0, stream>>>(ei, y, out, flag, E);
        k_final_fb<<<nblkN, 256, 0, stream>>>(dinv, b, out, N);
    }
}